// Round 9
// baseline (681.211 us; speedup 1.0000x reference)
//
#include <hip/hip_runtime.h>
#include <cstdint>
#include <cstddef>

#define NN 100000
#define IN_CH 165
#define HID 128

#define NBUCK 196     // ceil(100000/512) buckets of 512 nodes (dst>>9)
#define NPB 512
#define BMAX 10240    // max edges/bucket (mean 8163, +23 sigma)
#define NWG 256       // scatter/count workgroups

typedef __attribute__((ext_vector_type(8))) short short8;
typedef __attribute__((ext_vector_type(4))) float f32x4;

__device__ __forceinline__ ushort f2bf(float v) {
    uint b = __builtin_bit_cast(uint, v);
    return (ushort)((b + 0x7FFFu + ((b >> 16) & 1u)) >> 16);
}
__device__ __forceinline__ float bf2f(ushort u) {
    uint b = ((uint)u) << 16;
    return __builtin_bit_cast(float, b);
}
__device__ __forceinline__ float lo16f(uint u) { return __builtin_bit_cast(float, u << 16); }
__device__ __forceinline__ float hi16f(uint u) { return __builtin_bit_cast(float, u & 0xFFFF0000u); }

// ================= CSR build: 4-phase bucket sort, all stores coalesced =================
__global__ __launch_bounds__(256) void k_cnt(const int* __restrict__ dst, int E, int chunk,
                                             int* __restrict__ cnt) {
    __shared__ int h[NBUCK];
    const int w = blockIdx.x, t = threadIdx.x;
    for (int b = t; b < NBUCK; b += 256) h[b] = 0;
    __syncthreads();
    const int beg = w * chunk, end = min(E, beg + chunk);
    for (int i = beg + t; i < end; i += 256) atomicAdd(&h[dst[i] >> 9], 1);
    __syncthreads();
    for (int b = t; b < NBUCK; b += 256) cnt[w * NBUCK + b] = h[b];
}

// scan of the NWG x NBUCK count matrix in (b-major, w-minor) order; m = b*NWG + w
__global__ __launch_bounds__(256) void k_cscan(const int* __restrict__ cnt,
                                               int* __restrict__ gaddr) {
    __shared__ int ps[256];
    const int t = threadIdx.x;           // 50176 = 256 * 196
    int s = 0;
    for (int k = 0; k < NBUCK; k++) {
        const int m = t * NBUCK + k;
        s += cnt[(m & (NWG - 1)) * NBUCK + (m >> 8)];
    }
    ps[t] = s;
    __syncthreads();
    for (int off = 1; off < 256; off <<= 1) {
        int v = (t >= off) ? ps[t - off] : 0;
        __syncthreads();
        ps[t] += v;
        __syncthreads();
    }
    int run = (t > 0) ? ps[t - 1] : 0;
    for (int k = 0; k < NBUCK; k++) {
        const int m = t * NBUCK + k;
        gaddr[m] = run;
        run += cnt[(m & (NWG - 1)) * NBUCK + (m >> 8)];
    }
}

__global__ __launch_bounds__(256) void k_scatter(const int* __restrict__ src,
                                                 const int* __restrict__ dst, int E, int chunk,
                                                 const int* __restrict__ gaddr,
                                                 int* __restrict__ bdata) {
    __shared__ int cur[NBUCK];
    __shared__ int thist[256];
    __shared__ int sA[256];
    __shared__ int tex[NBUCK];
    __shared__ int lpos[NBUCK];
    __shared__ int staged[2048];
    __shared__ int addrs[2048];
    const int w = blockIdx.x, t = threadIdx.x;
    for (int b = t; b < NBUCK; b += 256) cur[b] = gaddr[b * NWG + w];
    const int beg = w * chunk, end = min(E, beg + chunk);
    for (int tb = beg; tb < end; tb += 2048) {
        const int tcnt = min(2048, end - tb);
        int key[8], bk[8];
#pragma unroll
        for (int j = 0; j < 8; j++) {
            const int i = tb + j * 256 + t;
            if (i < end) {
                const int d = dst[i];
                bk[j] = d >> 9;
                key[j] = (src[i] << 9) | (d & 511);
            } else bk[j] = -1;
        }
        __syncthreads();
        thist[t] = 0;
        __syncthreads();
#pragma unroll
        for (int j = 0; j < 8; j++)
            if (bk[j] >= 0) atomicAdd(&thist[bk[j]], 1);
        __syncthreads();
        sA[t] = thist[t];
        __syncthreads();
        for (int off = 1; off < 256; off <<= 1) {
            int v = (t >= off) ? sA[t - off] : 0;
            __syncthreads();
            sA[t] += v;
            __syncthreads();
        }
        if (t < NBUCK) {
            const int e = sA[t] - thist[t];
            tex[t] = e;
            lpos[t] = e;
        }
        __syncthreads();
#pragma unroll
        for (int j = 0; j < 8; j++)
            if (bk[j] >= 0) {
                const int b = bk[j];
                const int l = atomicAdd(&lpos[b], 1);
                staged[l] = key[j];
                addrs[l] = cur[b] + (l - tex[b]);
            }
        __syncthreads();
        for (int l = t; l < tcnt; l += 256) bdata[addrs[l]] = staged[l];
        __syncthreads();
        if (t < NBUCK) cur[t] += thist[t];
    }
}

__global__ __launch_bounds__(256) void k_csr2(const int* __restrict__ gaddr,
                                              const int* __restrict__ bdata, int E,
                                              int* __restrict__ csr, int* __restrict__ row_off,
                                              float* __restrict__ inv, int N) {
    __shared__ int keys[BMAX];
    __shared__ int sorted[BMAX];
    __shared__ int h5[NPB];
    __shared__ int s5[NPB];
    const int b = blockIdx.x, t = threadIdx.x;
    const int base = gaddr[b * NWG];
    const int nxt = (b == NBUCK - 1) ? E : gaddr[(b + 1) * NWG];
    const int tot = min(nxt - base, BMAX);
    for (int i = t; i < tot; i += 256) keys[i] = bdata[base + i];
    h5[t] = 0;
    h5[t + 256] = 0;
    __syncthreads();
    for (int i = t; i < tot; i += 256) atomicAdd(&h5[keys[i] & 511], 1);
    __syncthreads();
    s5[t] = h5[t];
    s5[t + 256] = h5[t + 256];
    __syncthreads();
    for (int off = 1; off < 512; off <<= 1) {
        const int a = (t >= off) ? s5[t - off] : 0;
        const int c = (t + 256 >= off) ? s5[t + 256 - off] : 0;
        __syncthreads();
        s5[t] += a;
        s5[t + 256] += c;
        __syncthreads();
    }
    const int e0 = s5[t] - h5[t];
    const int e1 = s5[t + 256] - h5[t + 256];
    __syncthreads();
    s5[t] = e0;
    s5[t + 256] = e1;
    const int n0 = b * NPB + t, n1 = b * NPB + t + 256;
    if (n0 < N) { row_off[n0] = base + e0; inv[n0] = 1.0f / (float)max(h5[t], 1); }
    if (n1 < N) { row_off[n1] = base + e1; inv[n1] = 1.0f / (float)max(h5[t + 256], 1); }
    if (b == 0 && t == 0) row_off[N] = E;
    __syncthreads();
    for (int i = t; i < tot; i += 256) {
        const int k = keys[i];
        const int p = atomicAdd(&s5[k & 511], 1);
        sorted[p] = k;
    }
    __syncthreads();
    for (int i = t; i < tot; i += 256) csr[base + i] = sorted[i] >> 9;
}

// ================= weight pack (bf16, k-blocked) — layers 0 and 1 only =================
__device__ __forceinline__ void wpack_one(const float* __restrict__ W, int K, int idx,
                                          ushort* __restrict__ Wh) {
    const int k = idx >> 7;
    const int j = idx & 127;
    const float v = (k < K) ? W[j * K + k] : 0.0f;
    const int o = (k >> 3) * (HID * 8) + j * 8 + (k & 7);
    Wh[o] = f2bf(v);
}

__global__ void k_wpack_all(const float* __restrict__ Wl0, const float* __restrict__ Wr0,
                            const float* __restrict__ Wl1, const float* __restrict__ Wr1,
                            ushort* __restrict__ Wl0h, ushort* __restrict__ Wr0h,
                            ushort* __restrict__ Wl1h, ushort* __restrict__ Wr1h) {
    const int gid = blockIdx.x * blockDim.x + threadIdx.x;
    if (gid < 192 * HID) {
        wpack_one(Wl0, IN_CH, gid, Wl0h);
        wpack_one(Wr0, IN_CH, gid, Wr0h);
    }
    if (gid < 128 * HID) {
        wpack_one(Wl1, HID, gid, Wl1h);
        wpack_one(Wr1, HID, gid, Wr1h);
    }
}

// ================= layer-2 weight fold: Wz=Wout@Wl2, Wrz=Wout@Wr2, bz=Wout@bl2+bout ======
// Wzp layout: [0..127]=Wz[0], [128..255]=Wz[1], [256..383]=Wrz[0], [384..511]=Wrz[1]
__global__ void k_wfold(const float* __restrict__ Wl2, const float* __restrict__ Wr2,
                        const float* __restrict__ Wout, const float* __restrict__ bl2,
                        const float* __restrict__ bout, float* __restrict__ Wzp,
                        float* __restrict__ bz) {
    const int t = threadIdx.x;      // 256
    const int c = t >> 7, k = t & 127;
    float sl = 0.f, sr = 0.f;
    for (int j = 0; j < 128; j++) {
        const float wo = Wout[c * 128 + j];
        sl += wo * Wl2[j * 128 + k];
        sr += wo * Wr2[j * 128 + k];
    }
    Wzp[c * 128 + k] = sl;
    Wzp[256 + c * 128 + k] = sr;
    if (t < 2) {
        float s = bout[t];
        for (int j = 0; j < 128; j++) s += Wout[t * 128 + j] * bl2[j];
        bz[t] = s;
    }
}

// ================= MFMA dual GEMM (pure bf16); yl -> 8 channel planes, yr row-major ======
template <typename TIN, int K, int KP>
__global__ __launch_bounds__(256) void k_gemm_mfma(
    const TIN* __restrict__ h,
    const ushort* __restrict__ Wlh, const ushort* __restrict__ Wrh,
    ushort* __restrict__ ylp, ushort* __restrict__ yr)
{
    constexpr int RS = KP * 2;  // LDS row stride (bytes)
    __shared__ __align__(16) char Ah[32 * RS];
    const int tid = threadIdx.x;
    const int node0 = blockIdx.x * 32;
    const TIN* __restrict__ hp = h + (size_t)node0 * K;

    if constexpr (sizeof(TIN) == 2) {
        constexpr int Q = 32 * (KP / 8);
        for (int q = tid; q < Q; q += 256) {
            const int r = q / (KP / 8);
            const int kp = (q - r * (KP / 8)) * 8;
            const short8 v = *reinterpret_cast<const short8*>(&hp[r * K + kp]);
            const int byte = r * RS + ((kp * 2) ^ ((r & 7) << 4));
            *reinterpret_cast<short8*>(Ah + byte) = v;
        }
    } else {
        constexpr int Q = 32 * (KP / 4);
        for (int q = tid; q < Q; q += 256) {
            const int r = q / (KP / 4);
            const int kp = (q - r * (KP / 4)) * 4;
            float v0, v1, v2, v3;
            if constexpr (K % 4 == 0) {
                const float4 v = *reinterpret_cast<const float4*>(&hp[r * K + kp]);
                v0 = v.x; v1 = v.y; v2 = v.z; v3 = v.w;
            } else {
                v0 = (kp + 0 < K) ? hp[r * K + kp + 0] : 0.0f;
                v1 = (kp + 1 < K) ? hp[r * K + kp + 1] : 0.0f;
                v2 = (kp + 2 < K) ? hp[r * K + kp + 2] : 0.0f;
                v3 = (kp + 3 < K) ? hp[r * K + kp + 3] : 0.0f;
            }
            const int byte = r * RS + ((kp * 2) ^ ((r & 7) << 4));
            *reinterpret_cast<ushort4*>(Ah + byte) =
                make_ushort4(f2bf(v0), f2bf(v1), f2bf(v2), f2bf(v3));
        }
    }
    __syncthreads();

    const int lane = tid & 63;
    const int w = tid >> 6;
    const int trow = lane & 15;
    const int kg = lane >> 4;
    const ushort* __restrict__ Bh = (w & 1) ? Wrh : Wlh;
    const int cb0 = (w >> 1) * 4;

    f32x4 acc[2][4];
#pragma unroll
    for (int a = 0; a < 2; ++a)
#pragma unroll
        for (int b = 0; b < 4; ++b) acc[a][b] = (f32x4){0.f, 0.f, 0.f, 0.f};

    const int xo = (trow & 7) << 4;
    const char* __restrict__ pA0 = Ah + trow * RS;
    const char* __restrict__ pA1 = Ah + (trow + 16) * RS;

    constexpr int KS = KP / 32;
    for (int ks = 0; ks < KS; ++ks) {
        const int kbyte = (ks * 64 + kg * 16) ^ xo;
        const short8 a0h = *reinterpret_cast<const short8*>(pA0 + kbyte);
        const short8 a1h = *reinterpret_cast<const short8*>(pA1 + kbyte);
        const int bbase = (ks * 4 + kg) * (HID * 8) + trow * 8;
#pragma unroll
        for (int ci = 0; ci < 4; ++ci) {
            const short8 bh = *reinterpret_cast<const short8*>(Bh + bbase + (cb0 + ci) * 128);
            acc[0][ci] = __builtin_amdgcn_mfma_f32_16x16x32_bf16(a0h, bh, acc[0][ci], 0, 0, 0);
            acc[1][ci] = __builtin_amdgcn_mfma_f32_16x16x32_bf16(a1h, bh, acc[1][ci], 0, 0, 0);
        }
    }

#pragma unroll
    for (int rb = 0; rb < 2; ++rb) {
        const int nb_ = node0 + rb * 16 + kg * 4;
#pragma unroll
        for (int ci = 0; ci < 4; ++ci) {
            const f32x4 a = acc[rb][ci];
            if (w & 1) {
                const int col = (cb0 + ci) * 16 + trow;
#pragma unroll
                for (int rr = 0; rr < 4; ++rr)
                    yr[(size_t)(nb_ + rr) * HID + col] = f2bf(a[rr]);
            } else {
                // plane store: plane = cb0+ci (0..7), ch = trow (0..15)
                const size_t pbase = (size_t)(cb0 + ci) * NN * 16 + trow;
#pragma unroll
                for (int rr = 0; rr < 4; ++rr)
                    ylp[pbase + (size_t)(nb_ + rr) * 16] = f2bf(a[rr]);
            }
        }
    }
}

// ================= plane-split aggregate+combine (layers 0,1; relu) ==================
// block b: plane p = b%8 (XCD round-robin pin), nodes (b/8)*4 .. +3, wave per node.
// lane = eslot*8 + c8: 8 edges per load instr, c8 covers 2 channels (uint).
__global__ __launch_bounds__(256) void k_aggp(
    const ushort* __restrict__ ylp, const int* __restrict__ row_off,
    const int* __restrict__ csr, const float* __restrict__ inv,
    const float* __restrict__ bias, const ushort* __restrict__ yr,
    ushort* __restrict__ hout, int N)
{
    const int p = blockIdx.x & 7;
    const int node = (blockIdx.x >> 3) * 4 + ((int)threadIdx.x >> 6);
    const int lane = threadIdx.x & 63;
    const int eslot = lane >> 3;
    const int c8 = lane & 7;
    const int beg = row_off[node];
    const int end = row_off[node + 1];
    const ushort* __restrict__ plane = ylp + (size_t)p * NN * 16;

    float a0 = 0.f, a1 = 0.f;
    int e = beg;
    for (; e + 16 <= end; e += 16) {
        const int s0 = csr[e + eslot];
        const int s1 = csr[e + 8 + eslot];
        const uint u0 = *reinterpret_cast<const uint*>(plane + (size_t)s0 * 16 + c8 * 2);
        const uint u1 = *reinterpret_cast<const uint*>(plane + (size_t)s1 * 16 + c8 * 2);
        a0 += lo16f(u0) + lo16f(u1);
        a1 += hi16f(u0) + hi16f(u1);
    }
    if (e + 8 <= end) {
        const int s0 = csr[e + eslot];
        const uint u0 = *reinterpret_cast<const uint*>(plane + (size_t)s0 * 16 + c8 * 2);
        a0 += lo16f(u0);
        a1 += hi16f(u0);
        e += 8;
    }
    if (e + eslot < end) {
        const int s0 = csr[e + eslot];
        const uint u0 = *reinterpret_cast<const uint*>(plane + (size_t)s0 * 16 + c8 * 2);
        a0 += lo16f(u0);
        a1 += hi16f(u0);
    }
    a0 += __shfl_xor(a0, 8);  a1 += __shfl_xor(a1, 8);
    a0 += __shfl_xor(a0, 16); a1 += __shfl_xor(a1, 16);
    a0 += __shfl_xor(a0, 32); a1 += __shfl_xor(a1, 32);

    if (lane < 8) {
        const float iv = inv[node];
        const int ch = p * 16 + c8 * 2;
        const uint rv = *reinterpret_cast<const uint*>(yr + (size_t)node * HID + ch);
        const float v0 = fmaxf(a0 * iv + bias[ch] + lo16f(rv), 0.f);
        const float v1 = fmaxf(a1 * iv + bias[ch + 1] + hi16f(rv), 0.f);
        *reinterpret_cast<uint*>(hout + (size_t)node * HID + ch) =
            (uint)f2bf(v0) | ((uint)f2bf(v1) << 16);
    }
}

// ================= layer-2 projection: z = h2@Wz^T, r = h2@Wrz^T (fp32 [N][2]) =========
__global__ __launch_bounds__(256) void k_zproj(
    const ushort* __restrict__ h2, const float* __restrict__ Wzp,
    float2* __restrict__ z, float2* __restrict__ r, int N)
{
    const int node = (blockIdx.x * 256 + (int)threadIdx.x) >> 6;
    const int lane = threadIdx.x & 63;
    if (node >= N) return;
    const uint u = *reinterpret_cast<const uint*>(h2 + (size_t)node * HID + lane * 2);
    const float hx = lo16f(u), hy = hi16f(u);
    float z0 = hx * Wzp[lane * 2] + hy * Wzp[lane * 2 + 1];
    float z1 = hx * Wzp[128 + lane * 2] + hy * Wzp[128 + lane * 2 + 1];
    float r0 = hx * Wzp[256 + lane * 2] + hy * Wzp[256 + lane * 2 + 1];
    float r1 = hx * Wzp[384 + lane * 2] + hy * Wzp[384 + lane * 2 + 1];
#pragma unroll
    for (int off = 32; off > 0; off >>= 1) {
        z0 += __shfl_xor(z0, off);
        z1 += __shfl_xor(z1, off);
        r0 += __shfl_xor(r0, off);
        r1 += __shfl_xor(r1, off);
    }
    if (lane == 0) {
        z[node] = make_float2(z0, z1);
        r[node] = make_float2(r0, r1);
    }
}

// ================= final aggregate on 8B rows -> out =================
__global__ __launch_bounds__(256) void k_aggz(
    const float2* __restrict__ z, const float2* __restrict__ r,
    const int* __restrict__ row_off, const int* __restrict__ csr,
    const float* __restrict__ inv, const float* __restrict__ bz,
    float2* __restrict__ out, int N)
{
    const int node = (blockIdx.x * 256 + (int)threadIdx.x) >> 6;
    const int lane = threadIdx.x & 63;
    if (node >= N) return;
    const int beg = row_off[node];
    const int end = row_off[node + 1];
    float s0 = 0.f, s1 = 0.f;
    for (int e = beg + lane; e < end; e += 64) {
        const float2 v = z[csr[e]];
        s0 += v.x;
        s1 += v.y;
    }
#pragma unroll
    for (int off = 32; off > 0; off >>= 1) {
        s0 += __shfl_xor(s0, off);
        s1 += __shfl_xor(s1, off);
    }
    if (lane == 0) {
        const float iv = inv[node];
        const float2 rv = r[node];
        out[node] = make_float2(s0 * iv + rv.x + bz[0], s1 * iv + rv.y + bz[1]);
    }
}

extern "C" void kernel_launch(void* const* d_in, const int* in_sizes, int n_in,
                              void* d_out, int out_size, void* d_ws, size_t ws_size,
                              hipStream_t stream) {
    const float* x    = (const float*)d_in[0];
    const int*   ei   = (const int*)d_in[1];
    const float* Wl0  = (const float*)d_in[2];
    const float* bl0  = (const float*)d_in[3];
    const float* Wr0  = (const float*)d_in[4];
    const float* Wl1  = (const float*)d_in[5];
    const float* bl1  = (const float*)d_in[6];
    const float* Wr1  = (const float*)d_in[7];
    const float* Wl2  = (const float*)d_in[8];
    const float* bl2  = (const float*)d_in[9];
    const float* Wr2  = (const float*)d_in[10];
    const float* Wout = (const float*)d_in[11];
    const float* bout = (const float*)d_in[12];

    const int N = NN;
    const int E = in_sizes[1] / 2;
    const int* src = ei;
    const int* dst = ei + E;
    const int chunk = (E + NWG - 1) / NWG;

    // workspace carve-up (256B aligned)
    char* w = (char*)d_ws;
    auto alloc = [&](size_t bytes) {
        char* p = w;
        w += (bytes + 255) & ~(size_t)255;
        return p;
    };
    int*    cnt     = (int*)alloc((size_t)NWG * NBUCK * 4);
    int*    gaddr   = (int*)alloc((size_t)NWG * NBUCK * 4);
    int*    bdata   = (int*)alloc((size_t)E * 4);
    int*    row_off = (int*)alloc((size_t)(N + 1) * 4);
    float*  inv     = (float*)alloc((size_t)N * 4);
    int*    csr     = (int*)alloc((size_t)E * 4);
    ushort* Wl0h    = (ushort*)alloc((size_t)192 * HID * 2);
    ushort* Wr0h    = (ushort*)alloc((size_t)192 * HID * 2);
    ushort* Wl1h    = (ushort*)alloc((size_t)HID * HID * 2);
    ushort* Wr1h    = (ushort*)alloc((size_t)HID * HID * 2);
    float*  Wzp     = (float*)alloc((size_t)512 * 4);
    float*  bz      = (float*)alloc((size_t)8 * 4);
    ushort* B0      = (ushort*)alloc((size_t)N * HID * 2);   // yl planes [8][N][16]
    ushort* B1      = (ushort*)alloc((size_t)N * HID * 2);   // yr / h row-major
    ushort* B2      = (ushort*)alloc((size_t)N * HID * 2);   // yr / h row-major
    float*  zbuf    = (float*)alloc((size_t)N * 2 * 4);
    float*  rbuf    = (float*)alloc((size_t)N * 2 * 4);

    // ---- CSR build (4-phase, no global atomics, coalesced stores) ----
    k_cnt<<<NWG, 256, 0, stream>>>(dst, E, chunk, cnt);
    k_cscan<<<1, 256, 0, stream>>>(cnt, gaddr);
    k_scatter<<<NWG, 256, 0, stream>>>(src, dst, E, chunk, gaddr, bdata);
    k_csr2<<<NBUCK, 256, 0, stream>>>(gaddr, bdata, E, csr, row_off, inv, N);

    // ---- weight packing + layer-2 fold ----
    k_wpack_all<<<(192 * HID + 255) / 256, 256, 0, stream>>>(
        Wl0, Wr0, Wl1, Wr1, Wl0h, Wr0h, Wl1h, Wr1h);
    k_wfold<<<1, 256, 0, stream>>>(Wl2, Wr2, Wout, bl2, bout, Wzp, bz);

    const int gemm_grid = N / 32;       // 3125
    const int aggp_grid = (N / 4) * 8;  // 200000 (plane = blk % 8)
    const int wave_grid = N / 4;        // 25000 (wave per node)

    // ---- layer 0: h = x (fp32, K=165 pad 192) ----
    k_gemm_mfma<float, IN_CH, 192><<<gemm_grid, 256, 0, stream>>>(x, Wl0h, Wr0h, B0, B1);
    k_aggp<<<aggp_grid, 256, 0, stream>>>(B0, row_off, csr, inv, bl0, B1, B1, N);

    // ---- layer 1 ----
    k_gemm_mfma<ushort, HID, HID><<<gemm_grid, 256, 0, stream>>>(B1, Wl1h, Wr1h, B0, B2);
    k_aggp<<<aggp_grid, 256, 0, stream>>>(B0, row_off, csr, inv, bl1, B2, B2, N);

    // ---- layer 2 collapsed through the linear head ----
    k_zproj<<<wave_grid, 256, 0, stream>>>(B2, Wzp, (float2*)zbuf, (float2*)rbuf, N);
    k_aggz<<<wave_grid, 256, 0, stream>>>((const float2*)zbuf, (const float2*)rbuf,
                                          row_off, csr, inv, bz, (float2*)d_out, N);
}

// Round 10
// 346.375 us; speedup vs baseline: 1.9667x; 1.9667x over previous
//
#include <hip/hip_runtime.h>
#include <cstdint>
#include <cstddef>

#define NN 100000
#define IN_CH 165
#define HID 128

#define NBUCK 196     // ceil(100000/512) buckets of 512 nodes (dst>>9)
#define NPB 512
#define BMAX 10240    // max edges/bucket (mean 8163, +23 sigma)
#define NWG 256       // scatter/count workgroups

typedef __attribute__((ext_vector_type(8))) short short8;
typedef __attribute__((ext_vector_type(4))) float f32x4;

__device__ __forceinline__ ushort f2bf(float v) {
    uint b = __builtin_bit_cast(uint, v);
    return (ushort)((b + 0x7FFFu + ((b >> 16) & 1u)) >> 16);
}
__device__ __forceinline__ float bf2f(ushort u) {
    uint b = ((uint)u) << 16;
    return __builtin_bit_cast(float, b);
}
__device__ __forceinline__ float lo16f(uint u) { return __builtin_bit_cast(float, u << 16); }
__device__ __forceinline__ float hi16f(uint u) { return __builtin_bit_cast(float, u & 0xFFFF0000u); }

// ================= CSR build: 4-phase bucket sort, all stores coalesced =================
__global__ __launch_bounds__(256) void k_cnt(const int* __restrict__ dst, int E, int chunk,
                                             int* __restrict__ cnt) {
    __shared__ int h[NBUCK];
    const int w = blockIdx.x, t = threadIdx.x;
    for (int b = t; b < NBUCK; b += 256) h[b] = 0;
    __syncthreads();
    const int beg = w * chunk, end = min(E, beg + chunk);
    for (int i = beg + t; i < end; i += 256) atomicAdd(&h[dst[i] >> 9], 1);
    __syncthreads();
    for (int b = t; b < NBUCK; b += 256) cnt[w * NBUCK + b] = h[b];
}

// scan of the NWG x NBUCK count matrix in (b-major, w-minor) order; m = b*NWG + w
__global__ __launch_bounds__(256) void k_cscan(const int* __restrict__ cnt,
                                               int* __restrict__ gaddr) {
    __shared__ int ps[256];
    const int t = threadIdx.x;           // 50176 = 256 * 196
    int s = 0;
    for (int k = 0; k < NBUCK; k++) {
        const int m = t * NBUCK + k;
        s += cnt[(m & (NWG - 1)) * NBUCK + (m >> 8)];
    }
    ps[t] = s;
    __syncthreads();
    for (int off = 1; off < 256; off <<= 1) {
        int v = (t >= off) ? ps[t - off] : 0;
        __syncthreads();
        ps[t] += v;
        __syncthreads();
    }
    int run = (t > 0) ? ps[t - 1] : 0;
    for (int k = 0; k < NBUCK; k++) {
        const int m = t * NBUCK + k;
        gaddr[m] = run;
        run += cnt[(m & (NWG - 1)) * NBUCK + (m >> 8)];
    }
}

__global__ __launch_bounds__(256) void k_scatter(const int* __restrict__ src,
                                                 const int* __restrict__ dst, int E, int chunk,
                                                 const int* __restrict__ gaddr,
                                                 int* __restrict__ bdata) {
    __shared__ int cur[NBUCK];
    __shared__ int thist[256];
    __shared__ int sA[256];
    __shared__ int tex[NBUCK];
    __shared__ int lpos[NBUCK];
    __shared__ int staged[2048];
    __shared__ int addrs[2048];
    const int w = blockIdx.x, t = threadIdx.x;
    for (int b = t; b < NBUCK; b += 256) cur[b] = gaddr[b * NWG + w];
    const int beg = w * chunk, end = min(E, beg + chunk);
    for (int tb = beg; tb < end; tb += 2048) {
        const int tcnt = min(2048, end - tb);
        int key[8], bk[8];
#pragma unroll
        for (int j = 0; j < 8; j++) {
            const int i = tb + j * 256 + t;
            if (i < end) {
                const int d = dst[i];
                bk[j] = d >> 9;
                key[j] = (src[i] << 9) | (d & 511);
            } else bk[j] = -1;
        }
        __syncthreads();
        thist[t] = 0;
        __syncthreads();
#pragma unroll
        for (int j = 0; j < 8; j++)
            if (bk[j] >= 0) atomicAdd(&thist[bk[j]], 1);
        __syncthreads();
        sA[t] = thist[t];
        __syncthreads();
        for (int off = 1; off < 256; off <<= 1) {
            int v = (t >= off) ? sA[t - off] : 0;
            __syncthreads();
            sA[t] += v;
            __syncthreads();
        }
        if (t < NBUCK) {
            const int e = sA[t] - thist[t];
            tex[t] = e;
            lpos[t] = e;
        }
        __syncthreads();
#pragma unroll
        for (int j = 0; j < 8; j++)
            if (bk[j] >= 0) {
                const int b = bk[j];
                const int l = atomicAdd(&lpos[b], 1);
                staged[l] = key[j];
                addrs[l] = cur[b] + (l - tex[b]);
            }
        __syncthreads();
        for (int l = t; l < tcnt; l += 256) bdata[addrs[l]] = staged[l];
        __syncthreads();
        if (t < NBUCK) cur[t] += thist[t];
    }
}

__global__ __launch_bounds__(256) void k_csr2(const int* __restrict__ gaddr,
                                              const int* __restrict__ bdata, int E,
                                              int* __restrict__ csr, int* __restrict__ row_off,
                                              float* __restrict__ inv, int N) {
    __shared__ int keys[BMAX];
    __shared__ int sorted[BMAX];
    __shared__ int h5[NPB];
    __shared__ int s5[NPB];
    const int b = blockIdx.x, t = threadIdx.x;
    const int base = gaddr[b * NWG];
    const int nxt = (b == NBUCK - 1) ? E : gaddr[(b + 1) * NWG];
    const int tot = min(nxt - base, BMAX);
    for (int i = t; i < tot; i += 256) keys[i] = bdata[base + i];
    h5[t] = 0;
    h5[t + 256] = 0;
    __syncthreads();
    for (int i = t; i < tot; i += 256) atomicAdd(&h5[keys[i] & 511], 1);
    __syncthreads();
    s5[t] = h5[t];
    s5[t + 256] = h5[t + 256];
    __syncthreads();
    for (int off = 1; off < 512; off <<= 1) {
        const int a = (t >= off) ? s5[t - off] : 0;
        const int c = (t + 256 >= off) ? s5[t + 256 - off] : 0;
        __syncthreads();
        s5[t] += a;
        s5[t + 256] += c;
        __syncthreads();
    }
    const int e0 = s5[t] - h5[t];
    const int e1 = s5[t + 256] - h5[t + 256];
    __syncthreads();
    s5[t] = e0;
    s5[t + 256] = e1;
    const int n0 = b * NPB + t, n1 = b * NPB + t + 256;
    if (n0 < N) { row_off[n0] = base + e0; inv[n0] = 1.0f / (float)max(h5[t], 1); }
    if (n1 < N) { row_off[n1] = base + e1; inv[n1] = 1.0f / (float)max(h5[t + 256], 1); }
    if (b == 0 && t == 0) row_off[N] = E;
    __syncthreads();
    for (int i = t; i < tot; i += 256) {
        const int k = keys[i];
        const int p = atomicAdd(&s5[k & 511], 1);
        sorted[p] = k;
    }
    __syncthreads();
    for (int i = t; i < tot; i += 256) csr[base + i] = sorted[i] >> 9;
}

// ================= weight pack (bf16, k-blocked) — layers 0 and 1 only =================
__device__ __forceinline__ void wpack_one(const float* __restrict__ W, int K, int idx,
                                          ushort* __restrict__ Wh) {
    const int k = idx >> 7;
    const int j = idx & 127;
    const float v = (k < K) ? W[j * K + k] : 0.0f;
    const int o = (k >> 3) * (HID * 8) + j * 8 + (k & 7);
    Wh[o] = f2bf(v);
}

__global__ void k_wpack_all(const float* __restrict__ Wl0, const float* __restrict__ Wr0,
                            const float* __restrict__ Wl1, const float* __restrict__ Wr1,
                            ushort* __restrict__ Wl0h, ushort* __restrict__ Wr0h,
                            ushort* __restrict__ Wl1h, ushort* __restrict__ Wr1h) {
    const int gid = blockIdx.x * blockDim.x + threadIdx.x;
    if (gid < 192 * HID) {
        wpack_one(Wl0, IN_CH, gid, Wl0h);
        wpack_one(Wr0, IN_CH, gid, Wr0h);
    }
    if (gid < 128 * HID) {
        wpack_one(Wl1, HID, gid, Wl1h);
        wpack_one(Wr1, HID, gid, Wr1h);
    }
}

// ================= layer-2 weight fold: Wz=Wout@Wl2, Wrz=Wout@Wr2, bz=Wout@bl2+bout ======
// Wzp layout: [0..127]=Wz[0], [128..255]=Wz[1], [256..383]=Wrz[0], [384..511]=Wrz[1]
__global__ void k_wfold(const float* __restrict__ Wl2, const float* __restrict__ Wr2,
                        const float* __restrict__ Wout, const float* __restrict__ bl2,
                        const float* __restrict__ bout, float* __restrict__ Wzp,
                        float* __restrict__ bz) {
    const int t = threadIdx.x;      // 256
    const int c = t >> 7, k = t & 127;
    float sl = 0.f, sr = 0.f;
    for (int j = 0; j < 128; j++) {
        const float wo = Wout[c * 128 + j];
        sl += wo * Wl2[j * 128 + k];
        sr += wo * Wr2[j * 128 + k];
    }
    Wzp[c * 128 + k] = sl;
    Wzp[256 + c * 128 + k] = sr;
    if (t < 2) {
        float s = bout[t];
        for (int j = 0; j < 128; j++) s += Wout[t * 128 + j] * bl2[j];
        bz[t] = s;
    }
}

// ================= MFMA dual GEMM (pure bf16); outputs yl, yr both bf16, row-major ======
template <typename TIN, int K, int KP>
__global__ __launch_bounds__(256) void k_gemm_mfma(
    const TIN* __restrict__ h,
    const ushort* __restrict__ Wlh, const ushort* __restrict__ Wrh,
    ushort* __restrict__ yl, ushort* __restrict__ yr)
{
    constexpr int RS = KP * 2;  // LDS row stride (bytes)
    __shared__ __align__(16) char Ah[32 * RS];
    const int tid = threadIdx.x;
    const int node0 = blockIdx.x * 32;
    const TIN* __restrict__ hp = h + (size_t)node0 * K;

    if constexpr (sizeof(TIN) == 2) {
        constexpr int Q = 32 * (KP / 8);
        for (int q = tid; q < Q; q += 256) {
            const int r = q / (KP / 8);
            const int kp = (q - r * (KP / 8)) * 8;
            const short8 v = *reinterpret_cast<const short8*>(&hp[r * K + kp]);
            const int byte = r * RS + ((kp * 2) ^ ((r & 7) << 4));
            *reinterpret_cast<short8*>(Ah + byte) = v;
        }
    } else {
        constexpr int Q = 32 * (KP / 4);
        for (int q = tid; q < Q; q += 256) {
            const int r = q / (KP / 4);
            const int kp = (q - r * (KP / 4)) * 4;
            float v0, v1, v2, v3;
            if constexpr (K % 4 == 0) {
                const float4 v = *reinterpret_cast<const float4*>(&hp[r * K + kp]);
                v0 = v.x; v1 = v.y; v2 = v.z; v3 = v.w;
            } else {
                v0 = (kp + 0 < K) ? hp[r * K + kp + 0] : 0.0f;
                v1 = (kp + 1 < K) ? hp[r * K + kp + 1] : 0.0f;
                v2 = (kp + 2 < K) ? hp[r * K + kp + 2] : 0.0f;
                v3 = (kp + 3 < K) ? hp[r * K + kp + 3] : 0.0f;
            }
            const int byte = r * RS + ((kp * 2) ^ ((r & 7) << 4));
            *reinterpret_cast<ushort4*>(Ah + byte) =
                make_ushort4(f2bf(v0), f2bf(v1), f2bf(v2), f2bf(v3));
        }
    }
    __syncthreads();

    const int lane = tid & 63;
    const int w = tid >> 6;
    const int trow = lane & 15;
    const int kg = lane >> 4;
    const ushort* __restrict__ Bh = (w & 1) ? Wrh : Wlh;
    ushort* __restrict__ yo = (w & 1) ? yr : yl;
    const int cb0 = (w >> 1) * 4;

    f32x4 acc[2][4];
#pragma unroll
    for (int a = 0; a < 2; ++a)
#pragma unroll
        for (int b = 0; b < 4; ++b) acc[a][b] = (f32x4){0.f, 0.f, 0.f, 0.f};

    const int xo = (trow & 7) << 4;
    const char* __restrict__ pA0 = Ah + trow * RS;
    const char* __restrict__ pA1 = Ah + (trow + 16) * RS;

    constexpr int KS = KP / 32;
    for (int ks = 0; ks < KS; ++ks) {
        const int kbyte = (ks * 64 + kg * 16) ^ xo;
        const short8 a0h = *reinterpret_cast<const short8*>(pA0 + kbyte);
        const short8 a1h = *reinterpret_cast<const short8*>(pA1 + kbyte);
        const int bbase = (ks * 4 + kg) * (HID * 8) + trow * 8;
#pragma unroll
        for (int ci = 0; ci < 4; ++ci) {
            const short8 bh = *reinterpret_cast<const short8*>(Bh + bbase + (cb0 + ci) * 128);
            acc[0][ci] = __builtin_amdgcn_mfma_f32_16x16x32_bf16(a0h, bh, acc[0][ci], 0, 0, 0);
            acc[1][ci] = __builtin_amdgcn_mfma_f32_16x16x32_bf16(a1h, bh, acc[1][ci], 0, 0, 0);
        }
    }

#pragma unroll
    for (int rb = 0; rb < 2; ++rb) {
        const int nb_ = node0 + rb * 16 + kg * 4;
#pragma unroll
        for (int ci = 0; ci < 4; ++ci) {
            const int col = (cb0 + ci) * 16 + trow;
            const f32x4 a = acc[rb][ci];
#pragma unroll
            for (int rr = 0; rr < 4; ++rr)
                yo[(size_t)(nb_ + rr) * HID + col] = f2bf(a[rr]);
        }
    }
}

// ================= aggregate + combine (layers 0,1; relu); 4 edges per load-instr =======
// lane = eslot*16 + c: edge-slot eslot (0..3), column group c covers 8 channels (uint4).
__global__ __launch_bounds__(256) void k_agg2(
    const ushort* __restrict__ yl, const int* __restrict__ row_off,
    const int* __restrict__ csr, const float* __restrict__ inv,
    const float* __restrict__ bias, const ushort* __restrict__ yr,
    ushort* __restrict__ hout, int N)
{
    const int wid = (blockIdx.x * 256 + (int)threadIdx.x) >> 6;
    const int lane = threadIdx.x & 63;
    if (wid >= N) return;
    const int eslot = lane >> 4;
    const int c = lane & 15;
    const int beg = row_off[wid];
    const int end = row_off[wid + 1];
    const uint4* __restrict__ Y = (const uint4*)yl;   // 16 uint4 per row

    float a0 = 0.f, a1 = 0.f, a2 = 0.f, a3 = 0.f;
    float a4 = 0.f, a5 = 0.f, a6 = 0.f, a7 = 0.f;
    auto acc8 = [&](uint4 u) {
        a0 += lo16f(u.x); a1 += hi16f(u.x);
        a2 += lo16f(u.y); a3 += hi16f(u.y);
        a4 += lo16f(u.z); a5 += hi16f(u.z);
        a6 += lo16f(u.w); a7 += hi16f(u.w);
    };

    int e = beg;
    for (; e + 16 <= end; e += 16) {
        const int s0 = csr[e + eslot];
        const int s1 = csr[e + 4 + eslot];
        const int s2 = csr[e + 8 + eslot];
        const int s3 = csr[e + 12 + eslot];
        const uint4 u0 = Y[(size_t)s0 * 16 + c];
        const uint4 u1 = Y[(size_t)s1 * 16 + c];
        const uint4 u2 = Y[(size_t)s2 * 16 + c];
        const uint4 u3 = Y[(size_t)s3 * 16 + c];
        acc8(u0); acc8(u1); acc8(u2); acc8(u3);
    }
    if (e + 8 <= end) {
        const int s0 = csr[e + eslot];
        const int s1 = csr[e + 4 + eslot];
        const uint4 u0 = Y[(size_t)s0 * 16 + c];
        const uint4 u1 = Y[(size_t)s1 * 16 + c];
        acc8(u0); acc8(u1);
        e += 8;
    }
    if (e + 4 <= end) {
        const uint4 u0 = Y[(size_t)csr[e + eslot] * 16 + c];
        acc8(u0);
        e += 4;
    }
    if (e + eslot < end) {
        const uint4 u0 = Y[(size_t)csr[e + eslot] * 16 + c];
        acc8(u0);
    }

    a0 += __shfl_xor(a0, 16); a1 += __shfl_xor(a1, 16);
    a2 += __shfl_xor(a2, 16); a3 += __shfl_xor(a3, 16);
    a4 += __shfl_xor(a4, 16); a5 += __shfl_xor(a5, 16);
    a6 += __shfl_xor(a6, 16); a7 += __shfl_xor(a7, 16);
    a0 += __shfl_xor(a0, 32); a1 += __shfl_xor(a1, 32);
    a2 += __shfl_xor(a2, 32); a3 += __shfl_xor(a3, 32);
    a4 += __shfl_xor(a4, 32); a5 += __shfl_xor(a5, 32);
    a6 += __shfl_xor(a6, 32); a7 += __shfl_xor(a7, 32);

    if (lane < 16) {
        const float iv = inv[wid];
        const uint4 rv = ((const uint4*)yr)[(size_t)wid * 16 + lane];
        const float4 b0 = ((const float4*)bias)[lane * 2];
        const float4 b1 = ((const float4*)bias)[lane * 2 + 1];
        const float v0 = fmaxf(a0 * iv + b0.x + lo16f(rv.x), 0.f);
        const float v1 = fmaxf(a1 * iv + b0.y + hi16f(rv.x), 0.f);
        const float v2 = fmaxf(a2 * iv + b0.z + lo16f(rv.y), 0.f);
        const float v3 = fmaxf(a3 * iv + b0.w + hi16f(rv.y), 0.f);
        const float v4 = fmaxf(a4 * iv + b1.x + lo16f(rv.z), 0.f);
        const float v5 = fmaxf(a5 * iv + b1.y + hi16f(rv.z), 0.f);
        const float v6 = fmaxf(a6 * iv + b1.z + lo16f(rv.w), 0.f);
        const float v7 = fmaxf(a7 * iv + b1.w + hi16f(rv.w), 0.f);
        uint4 o;
        o.x = (uint)f2bf(v0) | ((uint)f2bf(v1) << 16);
        o.y = (uint)f2bf(v2) | ((uint)f2bf(v3) << 16);
        o.z = (uint)f2bf(v4) | ((uint)f2bf(v5) << 16);
        o.w = (uint)f2bf(v6) | ((uint)f2bf(v7) << 16);
        ((uint4*)hout)[(size_t)wid * 16 + lane] = o;
    }
}

// ================= layer-2 projection: z = h2@Wz^T, r = h2@Wrz^T (fp32 [N][2]) =========
__global__ __launch_bounds__(256) void k_zproj(
    const ushort* __restrict__ h2, const float* __restrict__ Wzp,
    float2* __restrict__ z, float2* __restrict__ r, int N)
{
    const int node = (blockIdx.x * 256 + (int)threadIdx.x) >> 6;
    const int lane = threadIdx.x & 63;
    if (node >= N) return;
    const uint u = *reinterpret_cast<const uint*>(h2 + (size_t)node * HID + lane * 2);
    const float hx = lo16f(u), hy = hi16f(u);
    float z0 = hx * Wzp[lane * 2] + hy * Wzp[lane * 2 + 1];
    float z1 = hx * Wzp[128 + lane * 2] + hy * Wzp[128 + lane * 2 + 1];
    float r0 = hx * Wzp[256 + lane * 2] + hy * Wzp[256 + lane * 2 + 1];
    float r1 = hx * Wzp[384 + lane * 2] + hy * Wzp[384 + lane * 2 + 1];
#pragma unroll
    for (int off = 32; off > 0; off >>= 1) {
        z0 += __shfl_xor(z0, off);
        z1 += __shfl_xor(z1, off);
        r0 += __shfl_xor(r0, off);
        r1 += __shfl_xor(r1, off);
    }
    if (lane == 0) {
        z[node] = make_float2(z0, z1);
        r[node] = make_float2(r0, r1);
    }
}

// ================= final aggregate on 8B rows -> out =================
__global__ __launch_bounds__(256) void k_aggz(
    const float2* __restrict__ z, const float2* __restrict__ r,
    const int* __restrict__ row_off, const int* __restrict__ csr,
    const float* __restrict__ inv, const float* __restrict__ bz,
    float2* __restrict__ out, int N)
{
    const int node = (blockIdx.x * 256 + (int)threadIdx.x) >> 6;
    const int lane = threadIdx.x & 63;
    if (node >= N) return;
    const int beg = row_off[node];
    const int end = row_off[node + 1];
    float s0 = 0.f, s1 = 0.f;
    for (int e = beg + lane; e < end; e += 64) {
        const float2 v = z[csr[e]];
        s0 += v.x;
        s1 += v.y;
    }
#pragma unroll
    for (int off = 32; off > 0; off >>= 1) {
        s0 += __shfl_xor(s0, off);
        s1 += __shfl_xor(s1, off);
    }
    if (lane == 0) {
        const float iv = inv[node];
        const float2 rv = r[node];
        out[node] = make_float2(s0 * iv + rv.x + bz[0], s1 * iv + rv.y + bz[1]);
    }
}

extern "C" void kernel_launch(void* const* d_in, const int* in_sizes, int n_in,
                              void* d_out, int out_size, void* d_ws, size_t ws_size,
                              hipStream_t stream) {
    const float* x    = (const float*)d_in[0];
    const int*   ei   = (const int*)d_in[1];
    const float* Wl0  = (const float*)d_in[2];
    const float* bl0  = (const float*)d_in[3];
    const float* Wr0  = (const float*)d_in[4];
    const float* Wl1  = (const float*)d_in[5];
    const float* bl1  = (const float*)d_in[6];
    const float* Wr1  = (const float*)d_in[7];
    const float* Wl2  = (const float*)d_in[8];
    const float* bl2  = (const float*)d_in[9];
    const float* Wr2  = (const float*)d_in[10];
    const float* Wout = (const float*)d_in[11];
    const float* bout = (const float*)d_in[12];

    const int N = NN;
    const int E = in_sizes[1] / 2;
    const int* src = ei;
    const int* dst = ei + E;
    const int chunk = (E + NWG - 1) / NWG;

    // workspace carve-up (256B aligned)
    char* w = (char*)d_ws;
    auto alloc = [&](size_t bytes) {
        char* p = w;
        w += (bytes + 255) & ~(size_t)255;
        return p;
    };
    int*    cnt     = (int*)alloc((size_t)NWG * NBUCK * 4);
    int*    gaddr   = (int*)alloc((size_t)NWG * NBUCK * 4);
    int*    bdata   = (int*)alloc((size_t)E * 4);
    int*    row_off = (int*)alloc((size_t)(N + 1) * 4);
    float*  inv     = (float*)alloc((size_t)N * 4);
    int*    csr     = (int*)alloc((size_t)E * 4);
    ushort* Wl0h    = (ushort*)alloc((size_t)192 * HID * 2);
    ushort* Wr0h    = (ushort*)alloc((size_t)192 * HID * 2);
    ushort* Wl1h    = (ushort*)alloc((size_t)HID * HID * 2);
    ushort* Wr1h    = (ushort*)alloc((size_t)HID * HID * 2);
    float*  Wzp     = (float*)alloc((size_t)512 * 4);
    float*  bz      = (float*)alloc((size_t)8 * 4);
    ushort* B0      = (ushort*)alloc((size_t)N * HID * 2);   // yl (bf16 messages)
    ushort* B1      = (ushort*)alloc((size_t)N * HID * 2);   // yr / h
    ushort* B2      = (ushort*)alloc((size_t)N * HID * 2);   // yr / h
    float*  zbuf    = (float*)alloc((size_t)N * 2 * 4);
    float*  rbuf    = (float*)alloc((size_t)N * 2 * 4);

    // ---- CSR build (4-phase, no global atomics, coalesced stores) ----
    k_cnt<<<NWG, 256, 0, stream>>>(dst, E, chunk, cnt);
    k_cscan<<<1, 256, 0, stream>>>(cnt, gaddr);
    k_scatter<<<NWG, 256, 0, stream>>>(src, dst, E, chunk, gaddr, bdata);
    k_csr2<<<NBUCK, 256, 0, stream>>>(gaddr, bdata, E, csr, row_off, inv, N);

    // ---- weight packing + layer-2 fold ----
    k_wpack_all<<<(192 * HID + 255) / 256, 256, 0, stream>>>(
        Wl0, Wr0, Wl1, Wr1, Wl0h, Wr0h, Wl1h, Wr1h);
    k_wfold<<<1, 256, 0, stream>>>(Wl2, Wr2, Wout, bl2, bout, Wzp, bz);

    const int gemm_grid = N / 32;   // 3125
    const int wave_grid = N / 4;    // 25000 (wave per node)

    // ---- layer 0: h = x (fp32, K=165 pad 192) ----
    k_gemm_mfma<float, IN_CH, 192><<<gemm_grid, 256, 0, stream>>>(x, Wl0h, Wr0h, B0, B1);
    k_agg2<<<wave_grid, 256, 0, stream>>>(B0, row_off, csr, inv, bl0, B1, B1, N);

    // ---- layer 1 ----
    k_gemm_mfma<ushort, HID, HID><<<gemm_grid, 256, 0, stream>>>(B1, Wl1h, Wr1h, B0, B2);
    k_agg2<<<wave_grid, 256, 0, stream>>>(B0, row_off, csr, inv, bl1, B2, B2, N);

    // ---- layer 2 collapsed through the linear head ----
    k_zproj<<<wave_grid, 256, 0, stream>>>(B2, Wzp, (float2*)zbuf, (float2*)rbuf, N);
    k_aggz<<<wave_grid, 256, 0, stream>>>((const float2*)zbuf, (const float2*)rbuf,
                                          row_off, csr, inv, bz, (float2*)d_out, N);
}

// Round 11
// 322.671 us; speedup vs baseline: 2.1112x; 1.0735x over previous
//
#include <hip/hip_runtime.h>
#include <cstdint>
#include <cstddef>

#define NN 100000
#define IN_CH 165
#define HID 128

#define NBUCK 196     // ceil(100000/512) buckets of 512 nodes (dst>>9)
#define NPB 512
#define BMAX 10240    // max edges/bucket (mean 8163, +23 sigma)
#define NWG 256       // scatter/count workgroups

typedef __attribute__((ext_vector_type(8))) short short8;
typedef __attribute__((ext_vector_type(4))) float f32x4;

__device__ __forceinline__ ushort f2bf(float v) {
    uint b = __builtin_bit_cast(uint, v);
    return (ushort)((b + 0x7FFFu + ((b >> 16) & 1u)) >> 16);
}
__device__ __forceinline__ float bf2f(ushort u) {
    uint b = ((uint)u) << 16;
    return __builtin_bit_cast(float, b);
}
__device__ __forceinline__ float lo16f(uint u) { return __builtin_bit_cast(float, u << 16); }
__device__ __forceinline__ float hi16f(uint u) { return __builtin_bit_cast(float, u & 0xFFFF0000u); }

// ================= CSR build: 4-phase bucket sort, all stores coalesced =================
__global__ __launch_bounds__(256) void k_cnt(const int* __restrict__ dst, int E, int chunk,
                                             int* __restrict__ cnt) {
    __shared__ int h[NBUCK];
    const int w = blockIdx.x, t = threadIdx.x;
    for (int b = t; b < NBUCK; b += 256) h[b] = 0;
    __syncthreads();
    const int beg = w * chunk, end = min(E, beg + chunk);
    for (int i = beg + t; i < end; i += 256) atomicAdd(&h[dst[i] >> 9], 1);
    __syncthreads();
    for (int b = t; b < NBUCK; b += 256) cnt[w * NBUCK + b] = h[b];
}

// scan of the NWG x NBUCK count matrix in (b-major, w-minor) order; m = b*NWG + w
// 1024 threads, 49 entries each (50176 = 1024*49)
__global__ __launch_bounds__(1024) void k_cscan(const int* __restrict__ cnt,
                                                int* __restrict__ gaddr) {
    __shared__ int ps[1024];
    const int t = threadIdx.x;
    int s = 0;
    for (int k = 0; k < 49; k++) {
        const int m = t * 49 + k;
        s += cnt[(m & (NWG - 1)) * NBUCK + (m >> 8)];
    }
    ps[t] = s;
    __syncthreads();
    for (int off = 1; off < 1024; off <<= 1) {
        int v = (t >= off) ? ps[t - off] : 0;
        __syncthreads();
        ps[t] += v;
        __syncthreads();
    }
    int run = (t > 0) ? ps[t - 1] : 0;
    for (int k = 0; k < 49; k++) {
        const int m = t * 49 + k;
        gaddr[m] = run;
        run += cnt[(m & (NWG - 1)) * NBUCK + (m >> 8)];
    }
}

__global__ __launch_bounds__(256) void k_scatter(const int* __restrict__ src,
                                                 const int* __restrict__ dst, int E, int chunk,
                                                 const int* __restrict__ gaddr,
                                                 int* __restrict__ bdata) {
    __shared__ int cur[NBUCK];
    __shared__ int thist[256];
    __shared__ int sA[256];
    __shared__ int tex[NBUCK];
    __shared__ int lpos[NBUCK];
    __shared__ int staged[2048];
    __shared__ int addrs[2048];
    const int w = blockIdx.x, t = threadIdx.x;
    for (int b = t; b < NBUCK; b += 256) cur[b] = gaddr[b * NWG + w];
    const int beg = w * chunk, end = min(E, beg + chunk);
    for (int tb = beg; tb < end; tb += 2048) {
        const int tcnt = min(2048, end - tb);
        int key[8], bk[8];
#pragma unroll
        for (int j = 0; j < 8; j++) {
            const int i = tb + j * 256 + t;
            if (i < end) {
                const int d = dst[i];
                bk[j] = d >> 9;
                key[j] = (src[i] << 9) | (d & 511);
            } else bk[j] = -1;
        }
        __syncthreads();
        thist[t] = 0;
        __syncthreads();
#pragma unroll
        for (int j = 0; j < 8; j++)
            if (bk[j] >= 0) atomicAdd(&thist[bk[j]], 1);
        __syncthreads();
        sA[t] = thist[t];
        __syncthreads();
        for (int off = 1; off < 256; off <<= 1) {
            int v = (t >= off) ? sA[t - off] : 0;
            __syncthreads();
            sA[t] += v;
            __syncthreads();
        }
        if (t < NBUCK) {
            const int e = sA[t] - thist[t];
            tex[t] = e;
            lpos[t] = e;
        }
        __syncthreads();
#pragma unroll
        for (int j = 0; j < 8; j++)
            if (bk[j] >= 0) {
                const int b = bk[j];
                const int l = atomicAdd(&lpos[b], 1);
                staged[l] = key[j];
                addrs[l] = cur[b] + (l - tex[b]);
            }
        __syncthreads();
        for (int l = t; l < tcnt; l += 256) bdata[addrs[l]] = staged[l];
        __syncthreads();
        if (t < NBUCK) cur[t] += thist[t];
    }
}

__global__ __launch_bounds__(256) void k_csr2(const int* __restrict__ gaddr,
                                              const int* __restrict__ bdata, int E,
                                              int* __restrict__ csr, int* __restrict__ row_off,
                                              float* __restrict__ inv, int N) {
    __shared__ int keys[BMAX];
    __shared__ int sorted[BMAX];
    __shared__ int h5[NPB];
    __shared__ int s5[NPB];
    const int b = blockIdx.x, t = threadIdx.x;
    const int base = gaddr[b * NWG];
    const int nxt = (b == NBUCK - 1) ? E : gaddr[(b + 1) * NWG];
    const int tot = min(nxt - base, BMAX);
    for (int i = t; i < tot; i += 256) keys[i] = bdata[base + i];
    h5[t] = 0;
    h5[t + 256] = 0;
    __syncthreads();
    for (int i = t; i < tot; i += 256) atomicAdd(&h5[keys[i] & 511], 1);
    __syncthreads();
    s5[t] = h5[t];
    s5[t + 256] = h5[t + 256];
    __syncthreads();
    for (int off = 1; off < 512; off <<= 1) {
        const int a = (t >= off) ? s5[t - off] : 0;
        const int c = (t + 256 >= off) ? s5[t + 256 - off] : 0;
        __syncthreads();
        s5[t] += a;
        s5[t + 256] += c;
        __syncthreads();
    }
    const int e0 = s5[t] - h5[t];
    const int e1 = s5[t + 256] - h5[t + 256];
    __syncthreads();
    s5[t] = e0;
    s5[t + 256] = e1;
    const int n0 = b * NPB + t, n1 = b * NPB + t + 256;
    if (n0 < N) { row_off[n0] = base + e0; inv[n0] = 1.0f / (float)max(h5[t], 1); }
    if (n1 < N) { row_off[n1] = base + e1; inv[n1] = 1.0f / (float)max(h5[t + 256], 1); }
    if (b == 0 && t == 0) row_off[N] = E;
    __syncthreads();
    for (int i = t; i < tot; i += 256) {
        const int k = keys[i];
        const int p = atomicAdd(&s5[k & 511], 1);
        sorted[p] = k;
    }
    __syncthreads();
    for (int i = t; i < tot; i += 256) csr[base + i] = sorted[i] >> 9;
}

// ========== prep: weight pack (blocks 0..95) + layer-2 fold (block 96) ==========
__device__ __forceinline__ void wpack_one(const float* __restrict__ W, int K, int idx,
                                          ushort* __restrict__ Wh) {
    const int k = idx >> 7;
    const int j = idx & 127;
    const float v = (k < K) ? W[j * K + k] : 0.0f;
    const int o = (k >> 3) * (HID * 8) + j * 8 + (k & 7);
    Wh[o] = f2bf(v);
}

__global__ __launch_bounds__(256) void k_prep(
    const float* __restrict__ Wl0, const float* __restrict__ Wr0,
    const float* __restrict__ Wl1, const float* __restrict__ Wr1,
    const float* __restrict__ Wl2, const float* __restrict__ Wr2,
    const float* __restrict__ Wout, const float* __restrict__ bl2,
    const float* __restrict__ bout,
    ushort* __restrict__ Wl0h, ushort* __restrict__ Wr0h,
    ushort* __restrict__ Wl1h, ushort* __restrict__ Wr1h,
    float* __restrict__ Wzp, float* __restrict__ bz)
{
    if (blockIdx.x == 96) {
        // layer-2 fold: Wz=Wout@Wl2, Wrz=Wout@Wr2, bz=Wout@bl2+bout
        const int t = threadIdx.x;
        const int c = t >> 7, k = t & 127;
        float sl = 0.f, sr = 0.f;
        for (int j = 0; j < 128; j++) {
            const float wo = Wout[c * 128 + j];
            sl += wo * Wl2[j * 128 + k];
            sr += wo * Wr2[j * 128 + k];
        }
        Wzp[c * 128 + k] = sl;
        Wzp[256 + c * 128 + k] = sr;
        if (t < 2) {
            float s = bout[t];
            for (int j = 0; j < 128; j++) s += Wout[t * 128 + j] * bl2[j];
            bz[t] = s;
        }
        return;
    }
    const int gid = blockIdx.x * 256 + threadIdx.x;
    if (gid < 192 * HID) {
        wpack_one(Wl0, IN_CH, gid, Wl0h);
        wpack_one(Wr0, IN_CH, gid, Wr0h);
    }
    if (gid < 128 * HID) {
        wpack_one(Wl1, HID, gid, Wl1h);
        wpack_one(Wr1, HID, gid, Wr1h);
    }
}

// ================= MFMA dual GEMM (pure bf16); outputs yl, yr both bf16, row-major ======
template <typename TIN, int K, int KP>
__global__ __launch_bounds__(256) void k_gemm_mfma(
    const TIN* __restrict__ h,
    const ushort* __restrict__ Wlh, const ushort* __restrict__ Wrh,
    ushort* __restrict__ yl, ushort* __restrict__ yr)
{
    constexpr int RS = KP * 2;  // LDS row stride (bytes)
    __shared__ __align__(16) char Ah[32 * RS];
    const int tid = threadIdx.x;
    const int node0 = blockIdx.x * 32;
    const TIN* __restrict__ hp = h + (size_t)node0 * K;

    if constexpr (sizeof(TIN) == 2) {
        constexpr int Q = 32 * (KP / 8);
        for (int q = tid; q < Q; q += 256) {
            const int r = q / (KP / 8);
            const int kp = (q - r * (KP / 8)) * 8;
            const short8 v = *reinterpret_cast<const short8*>(&hp[r * K + kp]);
            const int byte = r * RS + ((kp * 2) ^ ((r & 7) << 4));
            *reinterpret_cast<short8*>(Ah + byte) = v;
        }
    } else {
        constexpr int Q = 32 * (KP / 4);
        for (int q = tid; q < Q; q += 256) {
            const int r = q / (KP / 4);
            const int kp = (q - r * (KP / 4)) * 4;
            float v0, v1, v2, v3;
            if constexpr (K % 4 == 0) {
                const float4 v = *reinterpret_cast<const float4*>(&hp[r * K + kp]);
                v0 = v.x; v1 = v.y; v2 = v.z; v3 = v.w;
            } else {
                v0 = (kp + 0 < K) ? hp[r * K + kp + 0] : 0.0f;
                v1 = (kp + 1 < K) ? hp[r * K + kp + 1] : 0.0f;
                v2 = (kp + 2 < K) ? hp[r * K + kp + 2] : 0.0f;
                v3 = (kp + 3 < K) ? hp[r * K + kp + 3] : 0.0f;
            }
            const int byte = r * RS + ((kp * 2) ^ ((r & 7) << 4));
            *reinterpret_cast<ushort4*>(Ah + byte) =
                make_ushort4(f2bf(v0), f2bf(v1), f2bf(v2), f2bf(v3));
        }
    }
    __syncthreads();

    const int lane = tid & 63;
    const int w = tid >> 6;
    const int trow = lane & 15;
    const int kg = lane >> 4;
    const ushort* __restrict__ Bh = (w & 1) ? Wrh : Wlh;
    ushort* __restrict__ yo = (w & 1) ? yr : yl;
    const int cb0 = (w >> 1) * 4;

    f32x4 acc[2][4];
#pragma unroll
    for (int a = 0; a < 2; ++a)
#pragma unroll
        for (int b = 0; b < 4; ++b) acc[a][b] = (f32x4){0.f, 0.f, 0.f, 0.f};

    const int xo = (trow & 7) << 4;
    const char* __restrict__ pA0 = Ah + trow * RS;
    const char* __restrict__ pA1 = Ah + (trow + 16) * RS;

    constexpr int KS = KP / 32;
    for (int ks = 0; ks < KS; ++ks) {
        const int kbyte = (ks * 64 + kg * 16) ^ xo;
        const short8 a0h = *reinterpret_cast<const short8*>(pA0 + kbyte);
        const short8 a1h = *reinterpret_cast<const short8*>(pA1 + kbyte);
        const int bbase = (ks * 4 + kg) * (HID * 8) + trow * 8;
#pragma unroll
        for (int ci = 0; ci < 4; ++ci) {
            const short8 bh = *reinterpret_cast<const short8*>(Bh + bbase + (cb0 + ci) * 128);
            acc[0][ci] = __builtin_amdgcn_mfma_f32_16x16x32_bf16(a0h, bh, acc[0][ci], 0, 0, 0);
            acc[1][ci] = __builtin_amdgcn_mfma_f32_16x16x32_bf16(a1h, bh, acc[1][ci], 0, 0, 0);
        }
    }

#pragma unroll
    for (int rb = 0; rb < 2; ++rb) {
        const int nb_ = node0 + rb * 16 + kg * 4;
#pragma unroll
        for (int ci = 0; ci < 4; ++ci) {
            const int col = (cb0 + ci) * 16 + trow;
            const f32x4 a = acc[rb][ci];
#pragma unroll
            for (int rr = 0; rr < 4; ++rr)
                yo[(size_t)(nb_ + rr) * HID + col] = f2bf(a[rr]);
        }
    }
}

// ============ aggregate + combine; 4 edges per load-instr ============
// HEAD=0: h_next (bf16) = relu(mean + bias + yr) -> hout
// HEAD=1: h2 in regs; fused z = h2@Wz^T, r = h2@Wrz^T -> zbuf, rbuf (h2 never stored)
template <int HEAD>
__global__ __launch_bounds__(256) void k_agg2(
    const ushort* __restrict__ yl, const int* __restrict__ row_off,
    const int* __restrict__ csr, const float* __restrict__ inv,
    const float* __restrict__ bias, const ushort* __restrict__ yr,
    ushort* __restrict__ hout, const float* __restrict__ Wzp,
    float2* __restrict__ zb, float2* __restrict__ rb, int N)
{
    const int wid = (blockIdx.x * 256 + (int)threadIdx.x) >> 6;
    const int lane = threadIdx.x & 63;
    if (wid >= N) return;
    const int eslot = lane >> 4;
    const int c = lane & 15;
    const int beg = row_off[wid];
    const int end = row_off[wid + 1];
    const uint4* __restrict__ Y = (const uint4*)yl;   // 16 uint4 per row

    float a0 = 0.f, a1 = 0.f, a2 = 0.f, a3 = 0.f;
    float a4 = 0.f, a5 = 0.f, a6 = 0.f, a7 = 0.f;
    auto acc8 = [&](uint4 u) {
        a0 += lo16f(u.x); a1 += hi16f(u.x);
        a2 += lo16f(u.y); a3 += hi16f(u.y);
        a4 += lo16f(u.z); a5 += hi16f(u.z);
        a6 += lo16f(u.w); a7 += hi16f(u.w);
    };

    int e = beg;
    for (; e + 16 <= end; e += 16) {
        const int s0 = csr[e + eslot];
        const int s1 = csr[e + 4 + eslot];
        const int s2 = csr[e + 8 + eslot];
        const int s3 = csr[e + 12 + eslot];
        const uint4 u0 = Y[(size_t)s0 * 16 + c];
        const uint4 u1 = Y[(size_t)s1 * 16 + c];
        const uint4 u2 = Y[(size_t)s2 * 16 + c];
        const uint4 u3 = Y[(size_t)s3 * 16 + c];
        acc8(u0); acc8(u1); acc8(u2); acc8(u3);
    }
    if (e + 8 <= end) {
        const int s0 = csr[e + eslot];
        const int s1 = csr[e + 4 + eslot];
        const uint4 u0 = Y[(size_t)s0 * 16 + c];
        const uint4 u1 = Y[(size_t)s1 * 16 + c];
        acc8(u0); acc8(u1);
        e += 8;
    }
    if (e + 4 <= end) {
        const uint4 u0 = Y[(size_t)csr[e + eslot] * 16 + c];
        acc8(u0);
        e += 4;
    }
    if (e + eslot < end) {
        const uint4 u0 = Y[(size_t)csr[e + eslot] * 16 + c];
        acc8(u0);
    }

    a0 += __shfl_xor(a0, 16); a1 += __shfl_xor(a1, 16);
    a2 += __shfl_xor(a2, 16); a3 += __shfl_xor(a3, 16);
    a4 += __shfl_xor(a4, 16); a5 += __shfl_xor(a5, 16);
    a6 += __shfl_xor(a6, 16); a7 += __shfl_xor(a7, 16);
    a0 += __shfl_xor(a0, 32); a1 += __shfl_xor(a1, 32);
    a2 += __shfl_xor(a2, 32); a3 += __shfl_xor(a3, 32);
    a4 += __shfl_xor(a4, 32); a5 += __shfl_xor(a5, 32);
    a6 += __shfl_xor(a6, 32); a7 += __shfl_xor(a7, 32);

    if (lane < 16) {
        const float iv = inv[wid];
        const uint4 rv = ((const uint4*)yr)[(size_t)wid * 16 + lane];
        const float4 b0 = ((const float4*)bias)[lane * 2];
        const float4 b1 = ((const float4*)bias)[lane * 2 + 1];
        const float v0 = fmaxf(a0 * iv + b0.x + lo16f(rv.x), 0.f);
        const float v1 = fmaxf(a1 * iv + b0.y + hi16f(rv.x), 0.f);
        const float v2 = fmaxf(a2 * iv + b0.z + lo16f(rv.y), 0.f);
        const float v3 = fmaxf(a3 * iv + b0.w + hi16f(rv.y), 0.f);
        const float v4 = fmaxf(a4 * iv + b1.x + lo16f(rv.z), 0.f);
        const float v5 = fmaxf(a5 * iv + b1.y + hi16f(rv.z), 0.f);
        const float v6 = fmaxf(a6 * iv + b1.z + lo16f(rv.w), 0.f);
        const float v7 = fmaxf(a7 * iv + b1.w + hi16f(rv.w), 0.f);
        if constexpr (!HEAD) {
            uint4 o;
            o.x = (uint)f2bf(v0) | ((uint)f2bf(v1) << 16);
            o.y = (uint)f2bf(v2) | ((uint)f2bf(v3) << 16);
            o.z = (uint)f2bf(v4) | ((uint)f2bf(v5) << 16);
            o.w = (uint)f2bf(v6) | ((uint)f2bf(v7) << 16);
            ((uint4*)hout)[(size_t)wid * 16 + lane] = o;
        } else {
            // fused layer-2 projection: z = h2.Wz, r = h2.Wrz (8 channels per lane)
            const int ch = lane * 8;
            float z0 = 0.f, z1 = 0.f, r0 = 0.f, r1 = 0.f;
            const float vv[8] = {v0, v1, v2, v3, v4, v5, v6, v7};
#pragma unroll
            for (int j = 0; j < 8; j++) {
                z0 += vv[j] * Wzp[ch + j];
                z1 += vv[j] * Wzp[128 + ch + j];
                r0 += vv[j] * Wzp[256 + ch + j];
                r1 += vv[j] * Wzp[384 + ch + j];
            }
#pragma unroll
            for (int off = 8; off > 0; off >>= 1) {
                z0 += __shfl_xor(z0, off);
                z1 += __shfl_xor(z1, off);
                r0 += __shfl_xor(r0, off);
                r1 += __shfl_xor(r1, off);
            }
            if (lane == 0) {
                zb[wid] = make_float2(z0, z1);
                rb[wid] = make_float2(r0, r1);
            }
        }
    }
}

// ================= final aggregate on 8B rows -> out =================
__global__ __launch_bounds__(256) void k_aggz(
    const float2* __restrict__ z, const float2* __restrict__ r,
    const int* __restrict__ row_off, const int* __restrict__ csr,
    const float* __restrict__ inv, const float* __restrict__ bz,
    float2* __restrict__ out, int N)
{
    const int node = (blockIdx.x * 256 + (int)threadIdx.x) >> 6;
    const int lane = threadIdx.x & 63;
    if (node >= N) return;
    const int beg = row_off[node];
    const int end = row_off[node + 1];
    float s0 = 0.f, s1 = 0.f;
    for (int e = beg + lane; e < end; e += 64) {
        const float2 v = z[csr[e]];
        s0 += v.x;
        s1 += v.y;
    }
#pragma unroll
    for (int off = 32; off > 0; off >>= 1) {
        s0 += __shfl_xor(s0, off);
        s1 += __shfl_xor(s1, off);
    }
    if (lane == 0) {
        const float iv = inv[node];
        const float2 rv = r[node];
        out[node] = make_float2(s0 * iv + rv.x + bz[0], s1 * iv + rv.y + bz[1]);
    }
}

extern "C" void kernel_launch(void* const* d_in, const int* in_sizes, int n_in,
                              void* d_out, int out_size, void* d_ws, size_t ws_size,
                              hipStream_t stream) {
    const float* x    = (const float*)d_in[0];
    const int*   ei   = (const int*)d_in[1];
    const float* Wl0  = (const float*)d_in[2];
    const float* bl0  = (const float*)d_in[3];
    const float* Wr0  = (const float*)d_in[4];
    const float* Wl1  = (const float*)d_in[5];
    const float* bl1  = (const float*)d_in[6];
    const float* Wr1  = (const float*)d_in[7];
    const float* Wl2  = (const float*)d_in[8];
    const float* bl2  = (const float*)d_in[9];
    const float* Wr2  = (const float*)d_in[10];
    const float* Wout = (const float*)d_in[11];
    const float* bout = (const float*)d_in[12];

    const int N = NN;
    const int E = in_sizes[1] / 2;
    const int* src = ei;
    const int* dst = ei + E;
    const int chunk = (E + NWG - 1) / NWG;

    // workspace carve-up (256B aligned)
    char* w = (char*)d_ws;
    auto alloc = [&](size_t bytes) {
        char* p = w;
        w += (bytes + 255) & ~(size_t)255;
        return p;
    };
    int*    cnt     = (int*)alloc((size_t)NWG * NBUCK * 4);
    int*    gaddr   = (int*)alloc((size_t)NWG * NBUCK * 4);
    int*    bdata   = (int*)alloc((size_t)E * 4);
    int*    row_off = (int*)alloc((size_t)(N + 1) * 4);
    float*  inv     = (float*)alloc((size_t)N * 4);
    int*    csr     = (int*)alloc((size_t)E * 4);
    ushort* Wl0h    = (ushort*)alloc((size_t)192 * HID * 2);
    ushort* Wr0h    = (ushort*)alloc((size_t)192 * HID * 2);
    ushort* Wl1h    = (ushort*)alloc((size_t)HID * HID * 2);
    ushort* Wr1h    = (ushort*)alloc((size_t)HID * HID * 2);
    float*  Wzp     = (float*)alloc((size_t)512 * 4);
    float*  bz      = (float*)alloc((size_t)8 * 4);
    ushort* B0      = (ushort*)alloc((size_t)N * HID * 2);   // yl (bf16 messages)
    ushort* B1      = (ushort*)alloc((size_t)N * HID * 2);   // yr / h
    ushort* B2      = (ushort*)alloc((size_t)N * HID * 2);   // yr (layer 1)
    float*  zbuf    = (float*)alloc((size_t)N * 2 * 4);
    float*  rbuf    = (float*)alloc((size_t)N * 2 * 4);

    // ---- CSR build (4-phase, no global atomics, coalesced stores) ----
    k_cnt<<<NWG, 256, 0, stream>>>(dst, E, chunk, cnt);
    k_cscan<<<1, 1024, 0, stream>>>(cnt, gaddr);
    k_scatter<<<NWG, 256, 0, stream>>>(src, dst, E, chunk, gaddr, bdata);
    k_csr2<<<NBUCK, 256, 0, stream>>>(gaddr, bdata, E, csr, row_off, inv, N);

    // ---- weight packing + layer-2 fold (one launch) ----
    k_prep<<<97, 256, 0, stream>>>(Wl0, Wr0, Wl1, Wr1, Wl2, Wr2, Wout, bl2, bout,
                                   Wl0h, Wr0h, Wl1h, Wr1h, Wzp, bz);

    const int gemm_grid = N / 32;   // 3125
    const int wave_grid = N / 4;    // 25000 (wave per node)

    // ---- layer 0: h = x (fp32, K=165 pad 192) ----
    k_gemm_mfma<float, IN_CH, 192><<<gemm_grid, 256, 0, stream>>>(x, Wl0h, Wr0h, B0, B1);
    k_agg2<0><<<wave_grid, 256, 0, stream>>>(B0, row_off, csr, inv, bl0, B1, B1,
                                             nullptr, nullptr, nullptr, N);

    // ---- layer 1 (agg fused with layer-2 projection; h2 never materialized) ----
    k_gemm_mfma<ushort, HID, HID><<<gemm_grid, 256, 0, stream>>>(B1, Wl1h, Wr1h, B0, B2);
    k_agg2<1><<<wave_grid, 256, 0, stream>>>(B0, row_off, csr, inv, bl1, B2, nullptr,
                                             Wzp, (float2*)zbuf, (float2*)rbuf, N);

    // ---- final: out = mean_agg(z) + r + bz ----
    k_aggz<<<wave_grid, 256, 0, stream>>>((const float2*)zbuf, (const float2*)rbuf,
                                          row_off, csr, inv, bz, (float2*)d_out, N);
}

// Round 12
// 285.425 us; speedup vs baseline: 2.3867x; 1.1305x over previous
//
#include <hip/hip_runtime.h>
#include <cstdint>
#include <cstddef>

#define NN 100000
#define IN_CH 165
#define HID 128

#define NBUCK 196     // ceil(100000/512) buckets of 512 nodes (dst>>9)
#define NPB 512
#define BMAX 10240    // max edges/bucket (mean 8163, +23 sigma)
#define NWG 256       // scatter/count workgroups

typedef __attribute__((ext_vector_type(8))) short short8;
typedef __attribute__((ext_vector_type(4))) float f32x4;

__device__ __forceinline__ ushort f2bf(float v) {
    uint b = __builtin_bit_cast(uint, v);
    return (ushort)((b + 0x7FFFu + ((b >> 16) & 1u)) >> 16);
}
__device__ __forceinline__ float lo16f(uint u) { return __builtin_bit_cast(float, u << 16); }
__device__ __forceinline__ float hi16f(uint u) { return __builtin_bit_cast(float, u & 0xFFFF0000u); }

// ================= CSR build: 4-phase bucket sort, all stores coalesced =================
// counts stored transposed: cnt[b * NWG + w] so the scan reads/writes linearly
__global__ __launch_bounds__(256) void k_cnt(const int* __restrict__ dst, int E, int chunk,
                                             int* __restrict__ cnt) {
    __shared__ int h[NBUCK];
    const int w = blockIdx.x, t = threadIdx.x;
    for (int b = t; b < NBUCK; b += 256) h[b] = 0;
    __syncthreads();
    const int beg = w * chunk, end = min(E, beg + chunk);
    for (int i0 = beg + t * 8; i0 < end; i0 += 2048) {
        if (i0 + 8 <= end) {
            const int4 d0 = *reinterpret_cast<const int4*>(dst + i0);
            const int4 d1 = *reinterpret_cast<const int4*>(dst + i0 + 4);
            atomicAdd(&h[d0.x >> 9], 1);
            atomicAdd(&h[d0.y >> 9], 1);
            atomicAdd(&h[d0.z >> 9], 1);
            atomicAdd(&h[d0.w >> 9], 1);
            atomicAdd(&h[d1.x >> 9], 1);
            atomicAdd(&h[d1.y >> 9], 1);
            atomicAdd(&h[d1.z >> 9], 1);
            atomicAdd(&h[d1.w >> 9], 1);
        } else {
            for (int i = i0; i < end; ++i) atomicAdd(&h[dst[i] >> 9], 1);
        }
    }
    __syncthreads();
    for (int b = t; b < NBUCK; b += 256) cnt[b * NWG + w] = h[b];
}

// linear exclusive scan of 50176 = 1024*49 entries (m = b*NWG + w order)
__global__ __launch_bounds__(1024) void k_cscan(const int* __restrict__ cnt,
                                                int* __restrict__ gaddr) {
    __shared__ int ps[1024];
    const int t = threadIdx.x;
    int s = 0;
    for (int k = 0; k < 49; k++) s += cnt[t * 49 + k];
    ps[t] = s;
    __syncthreads();
    for (int off = 1; off < 1024; off <<= 1) {
        int v = (t >= off) ? ps[t - off] : 0;
        __syncthreads();
        ps[t] += v;
        __syncthreads();
    }
    int run = (t > 0) ? ps[t - 1] : 0;
    for (int k = 0; k < 49; k++) {
        const int m = t * 49 + k;
        gaddr[m] = run;
        run += cnt[m];
    }
}

__global__ __launch_bounds__(256) void k_scatter(const int* __restrict__ src,
                                                 const int* __restrict__ dst, int E, int chunk,
                                                 const int* __restrict__ gaddr,
                                                 int* __restrict__ bdata) {
    __shared__ int cur[NBUCK];
    __shared__ int thist[256];
    __shared__ int sA[256];
    __shared__ int tex[NBUCK];
    __shared__ int lpos[NBUCK];
    __shared__ int staged[2048];
    __shared__ int addrs[2048];
    const int w = blockIdx.x, t = threadIdx.x;
    for (int b = t; b < NBUCK; b += 256) cur[b] = gaddr[b * NWG + w];
    const int beg = w * chunk, end = min(E, beg + chunk);
    for (int tb = beg; tb < end; tb += 2048) {
        const int tcnt = min(2048, end - tb);
        int key[8], bk[8];
        const int i0 = tb + t * 8;
        if (i0 + 8 <= end) {
            const int4 d0 = *reinterpret_cast<const int4*>(dst + i0);
            const int4 d1 = *reinterpret_cast<const int4*>(dst + i0 + 4);
            const int4 s0 = *reinterpret_cast<const int4*>(src + i0);
            const int4 s1 = *reinterpret_cast<const int4*>(src + i0 + 4);
            bk[0] = d0.x >> 9; key[0] = (s0.x << 9) | (d0.x & 511);
            bk[1] = d0.y >> 9; key[1] = (s0.y << 9) | (d0.y & 511);
            bk[2] = d0.z >> 9; key[2] = (s0.z << 9) | (d0.z & 511);
            bk[3] = d0.w >> 9; key[3] = (s0.w << 9) | (d0.w & 511);
            bk[4] = d1.x >> 9; key[4] = (s1.x << 9) | (d1.x & 511);
            bk[5] = d1.y >> 9; key[5] = (s1.y << 9) | (d1.y & 511);
            bk[6] = d1.z >> 9; key[6] = (s1.z << 9) | (d1.z & 511);
            bk[7] = d1.w >> 9; key[7] = (s1.w << 9) | (d1.w & 511);
        } else {
#pragma unroll
            for (int j = 0; j < 8; j++) {
                const int i = i0 + j;
                if (i < end) {
                    const int d = dst[i];
                    bk[j] = d >> 9;
                    key[j] = (src[i] << 9) | (d & 511);
                } else bk[j] = -1;
            }
        }
        __syncthreads();
        thist[t] = 0;
        __syncthreads();
#pragma unroll
        for (int j = 0; j < 8; j++)
            if (bk[j] >= 0) atomicAdd(&thist[bk[j]], 1);
        __syncthreads();
        sA[t] = thist[t];
        __syncthreads();
        for (int off = 1; off < 256; off <<= 1) {
            int v = (t >= off) ? sA[t - off] : 0;
            __syncthreads();
            sA[t] += v;
            __syncthreads();
        }
        if (t < NBUCK) {
            const int e = sA[t] - thist[t];
            tex[t] = e;
            lpos[t] = e;
        }
        __syncthreads();
#pragma unroll
        for (int j = 0; j < 8; j++)
            if (bk[j] >= 0) {
                const int b = bk[j];
                const int l = atomicAdd(&lpos[b], 1);
                staged[l] = key[j];
                addrs[l] = cur[b] + (l - tex[b]);
            }
        __syncthreads();
        for (int l = t; l < tcnt; l += 256) bdata[addrs[l]] = staged[l];
        __syncthreads();
        if (t < NBUCK) cur[t] += thist[t];
    }
}

__global__ __launch_bounds__(256) void k_csr2(const int* __restrict__ gaddr,
                                              const int* __restrict__ bdata, int E,
                                              int* __restrict__ csr, int* __restrict__ row_off,
                                              float* __restrict__ inv, int N) {
    __shared__ int keys[BMAX];
    __shared__ int sorted[BMAX];
    __shared__ int h5[NPB];
    __shared__ int s5[NPB];
    const int b = blockIdx.x, t = threadIdx.x;
    const int base = gaddr[b * NWG];
    const int nxt = (b == NBUCK - 1) ? E : gaddr[(b + 1) * NWG];
    const int tot = min(nxt - base, BMAX);
    for (int i = t; i < tot; i += 256) keys[i] = bdata[base + i];
    h5[t] = 0;
    h5[t + 256] = 0;
    __syncthreads();
    for (int i = t; i < tot; i += 256) atomicAdd(&h5[keys[i] & 511], 1);
    __syncthreads();
    s5[t] = h5[t];
    s5[t + 256] = h5[t + 256];
    __syncthreads();
    for (int off = 1; off < 512; off <<= 1) {
        const int a = (t >= off) ? s5[t - off] : 0;
        const int c = (t + 256 >= off) ? s5[t + 256 - off] : 0;
        __syncthreads();
        s5[t] += a;
        s5[t + 256] += c;
        __syncthreads();
    }
    const int e0 = s5[t] - h5[t];
    const int e1 = s5[t + 256] - h5[t + 256];
    __syncthreads();
    s5[t] = e0;
    s5[t + 256] = e1;
    const int n0 = b * NPB + t, n1 = b * NPB + t + 256;
    if (n0 < N) { row_off[n0] = base + e0; inv[n0] = 1.0f / (float)max(h5[t], 1); }
    if (n1 < N) { row_off[n1] = base + e1; inv[n1] = 1.0f / (float)max(h5[t + 256], 1); }
    if (b == 0 && t == 0) row_off[N] = E;
    __syncthreads();
    for (int i = t; i < tot; i += 256) {
        const int k = keys[i];
        const int p = atomicAdd(&s5[k & 511], 1);
        sorted[p] = k;
    }
    __syncthreads();
    for (int i = t; i < tot; i += 256) csr[base + i] = sorted[i] >> 9;
}

// ========== prep: weight pack (blocks 0..95) + layer-2 fold (block 96) ==========
__device__ __forceinline__ void wpack_one(const float* __restrict__ W, int K, int idx,
                                          ushort* __restrict__ Wh) {
    const int k = idx >> 7;
    const int j = idx & 127;
    const float v = (k < K) ? W[j * K + k] : 0.0f;
    const int o = (k >> 3) * (HID * 8) + j * 8 + (k & 7);
    Wh[o] = f2bf(v);
}

__global__ __launch_bounds__(256) void k_prep(
    const float* __restrict__ Wl0, const float* __restrict__ Wr0,
    const float* __restrict__ Wl1, const float* __restrict__ Wr1,
    const float* __restrict__ Wl2, const float* __restrict__ Wr2,
    const float* __restrict__ Wout, const float* __restrict__ bl2,
    const float* __restrict__ bout,
    ushort* __restrict__ Wl0h, ushort* __restrict__ Wr0h,
    ushort* __restrict__ Wl1h, ushort* __restrict__ Wr1h,
    float* __restrict__ Wzp, float* __restrict__ bz)
{
    if (blockIdx.x == 96) {
        const int t = threadIdx.x;
        const int c = t >> 7, k = t & 127;
        float sl = 0.f, sr = 0.f;
        for (int j = 0; j < 128; j++) {
            const float wo = Wout[c * 128 + j];
            sl += wo * Wl2[j * 128 + k];
            sr += wo * Wr2[j * 128 + k];
        }
        Wzp[c * 128 + k] = sl;
        Wzp[256 + c * 128 + k] = sr;
        if (t < 2) {
            float s = bout[t];
            for (int j = 0; j < 128; j++) s += Wout[t * 128 + j] * bl2[j];
            bz[t] = s;
        }
        return;
    }
    const int gid = blockIdx.x * 256 + threadIdx.x;
    if (gid < 192 * HID) {
        wpack_one(Wl0, IN_CH, gid, Wl0h);
        wpack_one(Wr0, IN_CH, gid, Wr0h);
    }
    if (gid < 128 * HID) {
        wpack_one(Wl1, HID, gid, Wl1h);
        wpack_one(Wr1, HID, gid, Wr1h);
    }
}

// ================= MFMA dual GEMM (pure bf16); outputs yl, yr both bf16, row-major ======
// fp32 path stages via raw LDS so all global reads are coalesced float4.
template <typename TIN, int K, int KP>
__global__ __launch_bounds__(256) void k_gemm_mfma(
    const TIN* __restrict__ h,
    const ushort* __restrict__ Wlh, const ushort* __restrict__ Wrh,
    ushort* __restrict__ yl, ushort* __restrict__ yr)
{
    constexpr int RS = KP * 2;  // LDS row stride (bytes)
    __shared__ __align__(16) char Ah[32 * RS];
    const int tid = threadIdx.x;
    const int node0 = blockIdx.x * 32;
    const TIN* __restrict__ hp = h + (size_t)node0 * K;

    if constexpr (sizeof(TIN) == 2) {
        constexpr int Q = 32 * (KP / 8);
        for (int q = tid; q < Q; q += 256) {
            const int r = q / (KP / 8);
            const int kp = (q - r * (KP / 8)) * 8;
            const short8 v = *reinterpret_cast<const short8*>(&hp[r * K + kp]);
            const int byte = r * RS + ((kp * 2) ^ ((r & 7) << 4));
            *reinterpret_cast<short8*>(Ah + byte) = v;
        }
    } else {
        // phase 1: flat coalesced float4 copy (32*K floats; tile base is 16B-aligned)
        __shared__ __align__(16) float raw[32 * K];
        const float* __restrict__ hpf = (const float*)hp;
        for (int i = tid * 4; i < 32 * K; i += 1024)
            *reinterpret_cast<float4*>(&raw[i]) = *reinterpret_cast<const float4*>(&hpf[i]);
        __syncthreads();
        // phase 2: LDS -> swizzled bf16 LDS (pad K..KP with zeros)
        constexpr int G = KP / 4;
        for (int q = tid; q < 32 * G; q += 256) {
            const int r = q / G;
            const int kp = (q - r * G) * 4;
            const float v0 = (kp + 0 < K) ? raw[r * K + kp + 0] : 0.0f;
            const float v1 = (kp + 1 < K) ? raw[r * K + kp + 1] : 0.0f;
            const float v2 = (kp + 2 < K) ? raw[r * K + kp + 2] : 0.0f;
            const float v3 = (kp + 3 < K) ? raw[r * K + kp + 3] : 0.0f;
            const int byte = r * RS + ((kp * 2) ^ ((r & 7) << 4));
            *reinterpret_cast<ushort4*>(Ah + byte) =
                make_ushort4(f2bf(v0), f2bf(v1), f2bf(v2), f2bf(v3));
        }
    }
    __syncthreads();

    const int lane = tid & 63;
    const int w = tid >> 6;
    const int trow = lane & 15;
    const int kg = lane >> 4;
    const ushort* __restrict__ Bh = (w & 1) ? Wrh : Wlh;
    ushort* __restrict__ yo = (w & 1) ? yr : yl;
    const int cb0 = (w >> 1) * 4;

    f32x4 acc[2][4];
#pragma unroll
    for (int a = 0; a < 2; ++a)
#pragma unroll
        for (int b = 0; b < 4; ++b) acc[a][b] = (f32x4){0.f, 0.f, 0.f, 0.f};

    const int xo = (trow & 7) << 4;
    const char* __restrict__ pA0 = Ah + trow * RS;
    const char* __restrict__ pA1 = Ah + (trow + 16) * RS;

    constexpr int KS = KP / 32;
    for (int ks = 0; ks < KS; ++ks) {
        const int kbyte = (ks * 64 + kg * 16) ^ xo;
        const short8 a0h = *reinterpret_cast<const short8*>(pA0 + kbyte);
        const short8 a1h = *reinterpret_cast<const short8*>(pA1 + kbyte);
        const int bbase = (ks * 4 + kg) * (HID * 8) + trow * 8;
#pragma unroll
        for (int ci = 0; ci < 4; ++ci) {
            const short8 bh = *reinterpret_cast<const short8*>(Bh + bbase + (cb0 + ci) * 128);
            acc[0][ci] = __builtin_amdgcn_mfma_f32_16x16x32_bf16(a0h, bh, acc[0][ci], 0, 0, 0);
            acc[1][ci] = __builtin_amdgcn_mfma_f32_16x16x32_bf16(a1h, bh, acc[1][ci], 0, 0, 0);
        }
    }

#pragma unroll
    for (int rb = 0; rb < 2; ++rb) {
        const int nb_ = node0 + rb * 16 + kg * 4;
#pragma unroll
        for (int ci = 0; ci < 4; ++ci) {
            const int col = (cb0 + ci) * 16 + trow;
            const f32x4 a = acc[rb][ci];
#pragma unroll
            for (int rr = 0; rr < 4; ++rr)
                yo[(size_t)(nb_ + rr) * HID + col] = f2bf(a[rr]);
        }
    }
}

// ============ shared gather body (macro-free; duplicated in two distinct kernels) ========
// lane = eslot*16 + c: 4 edges per load-instr, uint4 per lane (8 channels).

// ---- variant A: relu epilogue -> bf16 h_next ----
__global__ __launch_bounds__(256) void k_agg_relu(
    const ushort* __restrict__ yl, const int* __restrict__ row_off,
    const int* __restrict__ csr, const float* __restrict__ inv,
    const float* __restrict__ bias, const ushort* __restrict__ yr,
    ushort* __restrict__ hout, int N)
{
    const int wid = (blockIdx.x * 256 + (int)threadIdx.x) >> 6;
    const int lane = threadIdx.x & 63;
    if (wid >= N) return;
    const int eslot = lane >> 4;
    const int c = lane & 15;
    const int beg = row_off[wid];
    const int end = row_off[wid + 1];
    const uint4* __restrict__ Y = (const uint4*)yl;

    float a0 = 0.f, a1 = 0.f, a2 = 0.f, a3 = 0.f;
    float a4 = 0.f, a5 = 0.f, a6 = 0.f, a7 = 0.f;
    auto acc8 = [&](uint4 u) {
        a0 += lo16f(u.x); a1 += hi16f(u.x);
        a2 += lo16f(u.y); a3 += hi16f(u.y);
        a4 += lo16f(u.z); a5 += hi16f(u.z);
        a6 += lo16f(u.w); a7 += hi16f(u.w);
    };

    int e = beg;
    for (; e + 16 <= end; e += 16) {
        const int s0 = csr[e + eslot];
        const int s1 = csr[e + 4 + eslot];
        const int s2 = csr[e + 8 + eslot];
        const int s3 = csr[e + 12 + eslot];
        const uint4 u0 = Y[(size_t)s0 * 16 + c];
        const uint4 u1 = Y[(size_t)s1 * 16 + c];
        const uint4 u2 = Y[(size_t)s2 * 16 + c];
        const uint4 u3 = Y[(size_t)s3 * 16 + c];
        acc8(u0); acc8(u1); acc8(u2); acc8(u3);
    }
    if (e + 8 <= end) {
        const int s0 = csr[e + eslot];
        const int s1 = csr[e + 4 + eslot];
        const uint4 u0 = Y[(size_t)s0 * 16 + c];
        const uint4 u1 = Y[(size_t)s1 * 16 + c];
        acc8(u0); acc8(u1);
        e += 8;
    }
    if (e + 4 <= end) {
        const uint4 u0 = Y[(size_t)csr[e + eslot] * 16 + c];
        acc8(u0);
        e += 4;
    }
    if (e + eslot < end) {
        const uint4 u0 = Y[(size_t)csr[e + eslot] * 16 + c];
        acc8(u0);
    }

    a0 += __shfl_xor(a0, 16); a1 += __shfl_xor(a1, 16);
    a2 += __shfl_xor(a2, 16); a3 += __shfl_xor(a3, 16);
    a4 += __shfl_xor(a4, 16); a5 += __shfl_xor(a5, 16);
    a6 += __shfl_xor(a6, 16); a7 += __shfl_xor(a7, 16);
    a0 += __shfl_xor(a0, 32); a1 += __shfl_xor(a1, 32);
    a2 += __shfl_xor(a2, 32); a3 += __shfl_xor(a3, 32);
    a4 += __shfl_xor(a4, 32); a5 += __shfl_xor(a5, 32);
    a6 += __shfl_xor(a6, 32); a7 += __shfl_xor(a7, 32);

    if (lane < 16) {
        const float iv = inv[wid];
        const uint4 rv = ((const uint4*)yr)[(size_t)wid * 16 + lane];
        const float4 b0 = ((const float4*)bias)[lane * 2];
        const float4 b1 = ((const float4*)bias)[lane * 2 + 1];
        const float v0 = fmaxf(a0 * iv + b0.x + lo16f(rv.x), 0.f);
        const float v1 = fmaxf(a1 * iv + b0.y + hi16f(rv.x), 0.f);
        const float v2 = fmaxf(a2 * iv + b0.z + lo16f(rv.y), 0.f);
        const float v3 = fmaxf(a3 * iv + b0.w + hi16f(rv.y), 0.f);
        const float v4 = fmaxf(a4 * iv + b1.x + lo16f(rv.z), 0.f);
        const float v5 = fmaxf(a5 * iv + b1.y + hi16f(rv.z), 0.f);
        const float v6 = fmaxf(a6 * iv + b1.z + lo16f(rv.w), 0.f);
        const float v7 = fmaxf(a7 * iv + b1.w + hi16f(rv.w), 0.f);
        uint4 o;
        o.x = (uint)f2bf(v0) | ((uint)f2bf(v1) << 16);
        o.y = (uint)f2bf(v2) | ((uint)f2bf(v3) << 16);
        o.z = (uint)f2bf(v4) | ((uint)f2bf(v5) << 16);
        o.w = (uint)f2bf(v6) | ((uint)f2bf(v7) << 16);
        ((uint4*)hout)[(size_t)wid * 16 + lane] = o;
    }
}

// ---- variant B: relu + fused layer-2 projection epilogue -> z,r (h2 never stored) ----
__global__ __launch_bounds__(256) void k_agg_head(
    const ushort* __restrict__ yl, const int* __restrict__ row_off,
    const int* __restrict__ csr, const float* __restrict__ inv,
    const float* __restrict__ bias, const ushort* __restrict__ yr,
    const float* __restrict__ Wzp, float2* __restrict__ zb,
    float2* __restrict__ rb, int N)
{
    __shared__ float wz[512];
    for (int i = threadIdx.x; i < 512; i += 256) wz[i] = Wzp[i];
    __syncthreads();

    const int wid = (blockIdx.x * 256 + (int)threadIdx.x) >> 6;
    const int lane = threadIdx.x & 63;
    if (wid >= N) return;
    const int eslot = lane >> 4;
    const int c = lane & 15;
    const int beg = row_off[wid];
    const int end = row_off[wid + 1];
    const uint4* __restrict__ Y = (const uint4*)yl;

    float a0 = 0.f, a1 = 0.f, a2 = 0.f, a3 = 0.f;
    float a4 = 0.f, a5 = 0.f, a6 = 0.f, a7 = 0.f;
    auto acc8 = [&](uint4 u) {
        a0 += lo16f(u.x); a1 += hi16f(u.x);
        a2 += lo16f(u.y); a3 += hi16f(u.y);
        a4 += lo16f(u.z); a5 += hi16f(u.z);
        a6 += lo16f(u.w); a7 += hi16f(u.w);
    };

    int e = beg;
    for (; e + 16 <= end; e += 16) {
        const int s0 = csr[e + eslot];
        const int s1 = csr[e + 4 + eslot];
        const int s2 = csr[e + 8 + eslot];
        const int s3 = csr[e + 12 + eslot];
        const uint4 u0 = Y[(size_t)s0 * 16 + c];
        const uint4 u1 = Y[(size_t)s1 * 16 + c];
        const uint4 u2 = Y[(size_t)s2 * 16 + c];
        const uint4 u3 = Y[(size_t)s3 * 16 + c];
        acc8(u0); acc8(u1); acc8(u2); acc8(u3);
    }
    if (e + 8 <= end) {
        const int s0 = csr[e + eslot];
        const int s1 = csr[e + 4 + eslot];
        const uint4 u0 = Y[(size_t)s0 * 16 + c];
        const uint4 u1 = Y[(size_t)s1 * 16 + c];
        acc8(u0); acc8(u1);
        e += 8;
    }
    if (e + 4 <= end) {
        const uint4 u0 = Y[(size_t)csr[e + eslot] * 16 + c];
        acc8(u0);
        e += 4;
    }
    if (e + eslot < end) {
        const uint4 u0 = Y[(size_t)csr[e + eslot] * 16 + c];
        acc8(u0);
    }

    a0 += __shfl_xor(a0, 16); a1 += __shfl_xor(a1, 16);
    a2 += __shfl_xor(a2, 16); a3 += __shfl_xor(a3, 16);
    a4 += __shfl_xor(a4, 16); a5 += __shfl_xor(a5, 16);
    a6 += __shfl_xor(a6, 16); a7 += __shfl_xor(a7, 16);
    a0 += __shfl_xor(a0, 32); a1 += __shfl_xor(a1, 32);
    a2 += __shfl_xor(a2, 32); a3 += __shfl_xor(a3, 32);
    a4 += __shfl_xor(a4, 32); a5 += __shfl_xor(a5, 32);
    a6 += __shfl_xor(a6, 32); a7 += __shfl_xor(a7, 32);

    if (lane < 16) {
        const float iv = inv[wid];
        const uint4 rv = ((const uint4*)yr)[(size_t)wid * 16 + lane];
        const float4 b0 = ((const float4*)bias)[lane * 2];
        const float4 b1 = ((const float4*)bias)[lane * 2 + 1];
        const float v0 = fmaxf(a0 * iv + b0.x + lo16f(rv.x), 0.f);
        const float v1 = fmaxf(a1 * iv + b0.y + hi16f(rv.x), 0.f);
        const float v2 = fmaxf(a2 * iv + b0.z + lo16f(rv.y), 0.f);
        const float v3 = fmaxf(a3 * iv + b0.w + hi16f(rv.y), 0.f);
        const float v4 = fmaxf(a4 * iv + b1.x + lo16f(rv.z), 0.f);
        const float v5 = fmaxf(a5 * iv + b1.y + hi16f(rv.z), 0.f);
        const float v6 = fmaxf(a6 * iv + b1.z + lo16f(rv.w), 0.f);
        const float v7 = fmaxf(a7 * iv + b1.w + hi16f(rv.w), 0.f);
        const int ch = lane * 8;
        float z0 = 0.f, z1 = 0.f, r0 = 0.f, r1 = 0.f;
        const float vv[8] = {v0, v1, v2, v3, v4, v5, v6, v7};
#pragma unroll
        for (int j = 0; j < 8; j++) {
            z0 += vv[j] * wz[ch + j];
            z1 += vv[j] * wz[128 + ch + j];
            r0 += vv[j] * wz[256 + ch + j];
            r1 += vv[j] * wz[384 + ch + j];
        }
#pragma unroll
        for (int off = 8; off > 0; off >>= 1) {
            z0 += __shfl_xor(z0, off);
            z1 += __shfl_xor(z1, off);
            r0 += __shfl_xor(r0, off);
            r1 += __shfl_xor(r1, off);
        }
        if (lane == 0) {
            zb[wid] = make_float2(z0, z1);
            rb[wid] = make_float2(r0, r1);
        }
    }
}

// ================= final aggregate on 8B rows -> out =================
__global__ __launch_bounds__(256) void k_aggz(
    const float2* __restrict__ z, const float2* __restrict__ r,
    const int* __restrict__ row_off, const int* __restrict__ csr,
    const float* __restrict__ inv, const float* __restrict__ bz,
    float2* __restrict__ out, int N)
{
    const int node = (blockIdx.x * 256 + (int)threadIdx.x) >> 6;
    const int lane = threadIdx.x & 63;
    if (node >= N) return;
    const int beg = row_off[node];
    const int end = row_off[node + 1];
    float s0 = 0.f, s1 = 0.f;
    for (int e = beg + lane; e < end; e += 64) {
        const float2 v = z[csr[e]];
        s0 += v.x;
        s1 += v.y;
    }
#pragma unroll
    for (int off = 32; off > 0; off >>= 1) {
        s0 += __shfl_xor(s0, off);
        s1 += __shfl_xor(s1, off);
    }
    if (lane == 0) {
        const float iv = inv[node];
        const float2 rv = r[node];
        out[node] = make_float2(s0 * iv + rv.x + bz[0], s1 * iv + rv.y + bz[1]);
    }
}

extern "C" void kernel_launch(void* const* d_in, const int* in_sizes, int n_in,
                              void* d_out, int out_size, void* d_ws, size_t ws_size,
                              hipStream_t stream) {
    const float* x    = (const float*)d_in[0];
    const int*   ei   = (const int*)d_in[1];
    const float* Wl0  = (const float*)d_in[2];
    const float* bl0  = (const float*)d_in[3];
    const float* Wr0  = (const float*)d_in[4];
    const float* Wl1  = (const float*)d_in[5];
    const float* bl1  = (const float*)d_in[6];
    const float* Wr1  = (const float*)d_in[7];
    const float* Wl2  = (const float*)d_in[8];
    const float* bl2  = (const float*)d_in[9];
    const float* Wr2  = (const float*)d_in[10];
    const float* Wout = (const float*)d_in[11];
    const float* bout = (const float*)d_in[12];

    const int N = NN;
    const int E = in_sizes[1] / 2;
    const int* src = ei;
    const int* dst = ei + E;
    const int chunk = (((E + NWG - 1) / NWG) + 7) & ~7;   // multiple of 8 for int4 loads

    // workspace carve-up (256B aligned)
    char* w = (char*)d_ws;
    auto alloc = [&](size_t bytes) {
        char* p = w;
        w += (bytes + 255) & ~(size_t)255;
        return p;
    };
    int*    cnt     = (int*)alloc((size_t)NWG * NBUCK * 4);
    int*    gaddr   = (int*)alloc((size_t)NWG * NBUCK * 4);
    int*    bdata   = (int*)alloc((size_t)E * 4);
    int*    row_off = (int*)alloc((size_t)(N + 1) * 4);
    float*  inv     = (float*)alloc((size_t)N * 4);
    int*    csr     = (int*)alloc((size_t)E * 4);
    ushort* Wl0h    = (ushort*)alloc((size_t)192 * HID * 2);
    ushort* Wr0h    = (ushort*)alloc((size_t)192 * HID * 2);
    ushort* Wl1h    = (ushort*)alloc((size_t)HID * HID * 2);
    ushort* Wr1h    = (ushort*)alloc((size_t)HID * HID * 2);
    float*  Wzp     = (float*)alloc((size_t)512 * 4);
    float*  bz      = (float*)alloc((size_t)8 * 4);
    ushort* B0      = (ushort*)alloc((size_t)N * HID * 2);   // yl (bf16 messages)
    ushort* B1      = (ushort*)alloc((size_t)N * HID * 2);   // yr / h
    ushort* B2      = (ushort*)alloc((size_t)N * HID * 2);   // yr (layer 1)
    float*  zbuf    = (float*)alloc((size_t)N * 2 * 4);
    float*  rbuf    = (float*)alloc((size_t)N * 2 * 4);

    // ---- CSR build (4-phase, no global atomics, coalesced stores) ----
    k_cnt<<<NWG, 256, 0, stream>>>(dst, E, chunk, cnt);
    k_cscan<<<1, 1024, 0, stream>>>(cnt, gaddr);
    k_scatter<<<NWG, 256, 0, stream>>>(src, dst, E, chunk, gaddr, bdata);
    k_csr2<<<NBUCK, 256, 0, stream>>>(gaddr, bdata, E, csr, row_off, inv, N);

    // ---- weight packing + layer-2 fold (one launch) ----
    k_prep<<<97, 256, 0, stream>>>(Wl0, Wr0, Wl1, Wr1, Wl2, Wr2, Wout, bl2, bout,
                                   Wl0h, Wr0h, Wl1h, Wr1h, Wzp, bz);

    const int gemm_grid = N / 32;   // 3125
    const int wave_grid = N / 4;    // 25000 (wave per node)

    // ---- layer 0: h = x (fp32, K=165 pad 192) ----
    k_gemm_mfma<float, IN_CH, 192><<<gemm_grid, 256, 0, stream>>>(x, Wl0h, Wr0h, B0, B1);
    k_agg_relu<<<wave_grid, 256, 0, stream>>>(B0, row_off, csr, inv, bl0, B1, B1, N);

    // ---- layer 1 (agg fused with layer-2 projection; h2 never materialized) ----
    k_gemm_mfma<ushort, HID, HID><<<gemm_grid, 256, 0, stream>>>(B1, Wl1h, Wr1h, B0, B2);
    k_agg_head<<<wave_grid, 256, 0, stream>>>(B0, row_off, csr, inv, bl1, B2,
                                              Wzp, (float2*)zbuf, (float2*)rbuf, N);

    // ---- final: out = mean_agg(z) + r + bz ----
    k_aggz<<<wave_grid, 256, 0, stream>>>((const float2*)zbuf, (const float2*)rbuf,
                                          row_off, csr, inv, bz, (float2*)d_out, N);
}